// Round 1
// baseline (1404.736 us; speedup 1.0000x reference)
//
#include <hip/hip_runtime.h>
#include <hip/hip_bf16.h>
#include <cstdint>

constexpr int BB = 8;
constexpr int NN = 4096;
constexpr int KN = 10;     // K neighbors used
constexpr int KP = 11;     // K+1 stored
constexpr float EPS_BN = 1e-5f;
constexpr float TAU_V = 0.2f;
constexpr float INV_CNT = 1.0f / (float)(BB * NN * KN);

// ---------------------------------------------------------------- KNN
__global__ __launch_bounds__(128) void knn_kernel(const float* __restrict__ x,
                                                  int* __restrict__ nbr) {
  __shared__ float xs[NN], ys[NN], zs[NN], sq[NN];
  int b = blockIdx.y;
  int n = blockIdx.x * 128 + threadIdx.x;
  const float* xb = x + (size_t)b * NN * 5;
  for (int m = threadIdx.x; m < NN; m += 128) {
    float px = xb[m * 5 + 0], py = xb[m * 5 + 1], pz = xb[m * 5 + 2];
    xs[m] = px; ys[m] = py; zs[m] = pz;
    sq[m] = px * px + py * py + pz * pz;
  }
  __syncthreads();
  float qx = xs[n], qy = ys[n], qz = zs[n], qs = sq[n];
  float bd[KP]; int bi[KP];
#pragma unroll
  for (int j = 0; j < KP; ++j) { bd[j] = 3.4e38f; bi[j] = 0; }
  for (int m = 0; m < NN; ++m) {
    float d = qs + sq[m] - 2.0f * (qx * xs[m] + qy * ys[m] + qz * zs[m]);
    if (d < bd[KP - 1]) {
      bd[KP - 1] = d; bi[KP - 1] = m;
#pragma unroll
      for (int j = KP - 1; j > 0; --j) {
        if (bd[j] < bd[j - 1]) {
          float td = bd[j]; bd[j] = bd[j - 1]; bd[j - 1] = td;
          int ti = bi[j]; bi[j] = bi[j - 1]; bi[j - 1] = ti;
        }
      }
    }
  }
  int* o = nbr + ((size_t)b * NN + n) * KP;
#pragma unroll
  for (int j = 0; j < KP; ++j) o[j] = bi[j];
}

// ---------------------------------------------------------------- layer1 stats
// e1 = [cg-ci(3), ci(3), ag-ai(2), ai(2)] ; y = e1 @ W1 (10x64)
__device__ inline void stage_e1(const float* __restrict__ x, const int* __restrict__ nbr,
                                float (*e1s)[10], int b, int n0, int nedges, int tid, int nthreads) {
  for (int e = tid; e < nedges; e += nthreads) {
    int p = e / KN, k = e - p * KN;
    int n = n0 + p;
    const float* xn = x + ((size_t)b * NN + n) * 5;
    int g = nbr[((size_t)b * NN + n) * KP + k];  // idx1 = first K entries (incl self)
    const float* xg = x + ((size_t)b * NN + g) * 5;
    float cx = xn[0], cy = xn[1], cz = xn[2], a0 = xn[3], a1 = xn[4];
    e1s[e][0] = xg[0] - cx; e1s[e][1] = xg[1] - cy; e1s[e][2] = xg[2] - cz;
    e1s[e][3] = cx;         e1s[e][4] = cy;         e1s[e][5] = cz;
    e1s[e][6] = xg[3] - a0; e1s[e][7] = xg[4] - a1;
    e1s[e][8] = a0;         e1s[e][9] = a1;
  }
}

__global__ __launch_bounds__(256) void stats1_kernel(const float* __restrict__ x,
                                                     const int* __restrict__ nbr,
                                                     const float* __restrict__ W1,
                                                     float* __restrict__ stats) {
  constexpr int PPB = 32;
  __shared__ float e1s[PPB * KN][10];
  __shared__ float W1s[10][64];
  __shared__ float red[256];
  int b = blockIdx.y;
  int n0 = blockIdx.x * PPB;
  int tid = threadIdx.x;
  for (int i = tid; i < 640; i += 256) W1s[i / 64][i % 64] = W1[i];
  stage_e1(x, nbr, e1s, b, n0, PPB * KN, tid, 256);
  __syncthreads();
  int c = tid & 63, lane = tid >> 6;
  float s = 0.f, ss = 0.f;
  for (int e = lane; e < PPB * KN; e += 4) {
    float y = 0.f;
#pragma unroll
    for (int i = 0; i < 10; ++i) y = fmaf(e1s[e][i], W1s[i][c], y);
    s += y; ss += y * y;
  }
  red[tid] = s; __syncthreads();
  float s4 = 0.f, ss4 = 0.f;
  if (lane == 0) s4 = red[c] + red[c + 64] + red[c + 128] + red[c + 192];
  __syncthreads();
  red[tid] = ss; __syncthreads();
  if (lane == 0) {
    ss4 = red[c] + red[c + 64] + red[c + 128] + red[c + 192];
    atomicAdd(&stats[c], s4);
    atomicAdd(&stats[64 + c], ss4);
  }
}

__global__ __launch_bounds__(256) void apply1_kernel(const float* __restrict__ x,
                                                     const int* __restrict__ nbr,
                                                     const float* __restrict__ W1,
                                                     const float* __restrict__ g1,
                                                     const float* __restrict__ b1,
                                                     const float* __restrict__ stats,
                                                     float* __restrict__ f1) {
  constexpr int PPB = 16;
  __shared__ float e1s[PPB * KN][10];
  __shared__ float W1s[10][64];
  int b = blockIdx.y;
  int n0 = blockIdx.x * PPB;
  int tid = threadIdx.x;
  for (int i = tid; i < 640; i += 256) W1s[i / 64][i % 64] = W1[i];
  stage_e1(x, nbr, e1s, b, n0, PPB * KN, tid, 256);
  __syncthreads();
  int c = tid & 63, pl = tid >> 6;
  float mean = stats[c] * INV_CNT;
  float var = stats[64 + c] * INV_CNT - mean * mean;
  float scale = g1[c] * rsqrtf(var + EPS_BN);
  float shift = b1[c] - mean * scale;
  for (int p = pl; p < PPB; p += 4) {
    float mx = 0.0f;  // relu outputs are >= 0
#pragma unroll
    for (int k = 0; k < KN; ++k) {
      float y = 0.f;
#pragma unroll
      for (int i = 0; i < 10; ++i) y = fmaf(e1s[p * KN + k][i], W1s[i][c], y);
      float h = scale * y + shift;
      mx = fmaxf(mx, h);
    }
    f1[((size_t)b * NN + n0 + p) * 64 + c] = mx;
  }
}

// ---------------------------------------------------------------- weight packing
// dst[k][j] for k<Kh, j<2*Nout:  j<Nout -> src[k][j]  (u part)
//                                j>=Nout -> src[Kh+k][j-Nout]-src[k][j-Nout] (d part)
__global__ void pack_kernel(const float* __restrict__ src, float* __restrict__ dst,
                            int Kh, int Nout) {
  int idx = blockIdx.x * 256 + threadIdx.x;
  int tot = Kh * 2 * Nout;
  if (idx >= tot) return;
  int k = idx / (2 * Nout);
  int j = idx - k * 2 * Nout;
  float v;
  if (j < Nout) v = src[k * Nout + j];
  else { int jj = j - Nout; v = src[(Kh + k) * Nout + jj] - src[k * Nout + jj]; }
  dst[idx] = v;
}

// ---------------------------------------------------------------- simple tiled SGEMM
// C[M x Nc] = A[M x Kd] @ P[Kd x Nc], all row-major. M,Nc multiples of 64, Kd of 16.
template <int Kd>
__global__ __launch_bounds__(256) void gemm_kernel(const float* __restrict__ A,
                                                   const float* __restrict__ P,
                                                   float* __restrict__ C, int Nc) {
  __shared__ float As[64][17];
  __shared__ float Bs[16][64];
  int tid = threadIdx.x;
  int tx = tid & 15, ty = tid >> 4;
  int r0 = blockIdx.y * 64, c0 = blockIdx.x * 64;
  float acc[4][4] = {};
  for (int k0 = 0; k0 < Kd; k0 += 16) {
    for (int e = tid; e < 1024; e += 256) {
      int r = e >> 4, kk = e & 15;
      As[r][kk] = A[(size_t)(r0 + r) * Kd + k0 + kk];
    }
    for (int e = tid; e < 1024; e += 256) {
      int kk = e >> 6, cc = e & 63;
      Bs[kk][cc] = P[(size_t)(k0 + kk) * Nc + c0 + cc];
    }
    __syncthreads();
#pragma unroll
    for (int kk = 0; kk < 16; ++kk) {
      float a[4], bv[4];
#pragma unroll
      for (int i = 0; i < 4; ++i) a[i] = As[ty * 4 + i][kk];
#pragma unroll
      for (int j = 0; j < 4; ++j) bv[j] = Bs[kk][tx * 4 + j];
#pragma unroll
      for (int i = 0; i < 4; ++i)
#pragma unroll
        for (int j = 0; j < 4; ++j) acc[i][j] = fmaf(a[i], bv[j], acc[i][j]);
    }
    __syncthreads();
  }
#pragma unroll
  for (int i = 0; i < 4; ++i)
#pragma unroll
    for (int j = 0; j < 4; ++j)
      C[(size_t)(r0 + ty * 4 + i) * Nc + c0 + tx * 4 + j] = acc[i][j];
}

// ---------------------------------------------------------------- soft-edge stats
// U layout per point: [u(C) | d(C)] ; y_{n,k,c} = U[idx_k][c] + U[n][C+c]
template <int C>
__global__ __launch_bounds__(256) void soft_stats_kernel(const float* __restrict__ U,
                                                         const int* __restrict__ nbr,
                                                         float* __restrict__ stats) {
  constexpr int LANES = 256 / C;
  constexpr int PPB = (C == 128) ? 64 : 32;
  __shared__ float red[256];
  int tid = threadIdx.x;
  int c = tid % C;
  int lane = tid / C;
  int bn0 = blockIdx.x * PPB;
  float s = 0.f, ss = 0.f;
  for (int p = lane; p < PPB; p += LANES) {
    int bn = bn0 + p;
    int b = bn >> 12;
    float d = U[(size_t)bn * (2 * C) + C + c];
    const int* ix = nbr + (size_t)bn * KP;
#pragma unroll
    for (int k = 1; k <= KN; ++k) {  // idx = entries 1..K (excl self)
      int row = ix[k];
      float y = U[((size_t)(b << 12) + row) * (2 * C) + c] + d;
      s += y; ss += y * y;
    }
  }
  if (LANES == 2) {
    red[tid] = s; __syncthreads();
    float s2 = 0.f;
    if (tid < C) s2 = red[tid] + red[tid + C];
    __syncthreads();
    red[tid] = ss; __syncthreads();
    if (tid < C) {
      float ss2 = red[tid] + red[tid + C];
      atomicAdd(&stats[c], s2);
      atomicAdd(&stats[C + c], ss2);
    }
  } else {
    atomicAdd(&stats[c], s);
    atomicAdd(&stats[C + c], ss);
  }
}

// ---------------------------------------------------------------- soft-edge apply
template <int C, int CA>
__global__ __launch_bounds__(C) void soft_apply_kernel(const float* __restrict__ U,
                                                       const float* __restrict__ UA,
                                                       const int* __restrict__ nbr,
                                                       const float* __restrict__ stats,
                                                       const float* __restrict__ gbn,
                                                       const float* __restrict__ bbn,
                                                       const float* __restrict__ ba,
                                                       const float* __restrict__ Wb,
                                                       const float* __restrict__ bbv,
                                                       float* __restrict__ fout) {
  __shared__ int ixs[KN];
  __shared__ float logits[KN];
  __shared__ float parts[KN][2];
  int tid = threadIdx.x;
  int bn = blockIdx.x;
  int b = bn >> 12;
  if (tid < KN) ixs[tid] = nbr[(size_t)bn * KP + 1 + tid];
  __syncthreads();
  float pv[KN];
  if (tid < CA) {
    float da = UA[(size_t)bn * (2 * CA) + CA + tid] + ba[tid];
    float wbj = Wb[tid];
#pragma unroll
    for (int k = 0; k < KN; ++k) {
      int row = ixs[k];
      float h = UA[((size_t)(b << 12) + row) * (2 * CA) + tid] + da;
      h = fmaxf(h, 0.f);
      pv[k] = h * wbj;
    }
  } else {
#pragma unroll
    for (int k = 0; k < KN; ++k) pv[k] = 0.f;
  }
#pragma unroll
  for (int k = 0; k < KN; ++k) {
    float v = pv[k];
    for (int off = 32; off >= 1; off >>= 1) v += __shfl_down(v, off);
    if ((tid & 63) == 0 && tid < CA) parts[k][tid >> 6] = v;
  }
  __syncthreads();
  if (tid == 0) {
    float bsv = bbv[0];
#pragma unroll
    for (int k = 0; k < KN; ++k) {
      float l = parts[k][0];
      if (CA == 128) l += parts[k][1];
      logits[k] = (l + bsv) * (1.0f / TAU_V);
    }
  }
  __syncthreads();
  // redundant per-thread softmax over K
  float lg[KN], mx = -3.4e38f;
#pragma unroll
  for (int k = 0; k < KN; ++k) { lg[k] = logits[k]; mx = fmaxf(mx, lg[k]); }
  float se = 0.f;
#pragma unroll
  for (int k = 0; k < KN; ++k) { lg[k] = expf(lg[k] - mx); se += lg[k]; }
  float inv = 1.0f / se;
  int c = tid;
  float mean = stats[c] * INV_CNT;
  float var = stats[C + c] * INV_CNT - mean * mean;
  float scale = gbn[c] * rsqrtf(var + EPS_BN);
  float shift = bbn[c] - mean * scale;
  float d = U[(size_t)bn * (2 * C) + C + c];
  float acc = 0.f;
#pragma unroll
  for (int k = 0; k < KN; ++k) {
    int row = ixs[k];
    float y = U[((size_t)(b << 12) + row) * (2 * C) + c] + d;
    float h = fmaxf(scale * y + shift, 0.f);
    acc += h * lg[k];
  }
  fout[(size_t)bn * C + c] = acc * inv;
}

// ---------------------------------------------------------------- global attention pool
__global__ __launch_bounds__(256) void wlog_kernel(const float* __restrict__ f3,
                                                   const float* __restrict__ Wa1,
                                                   const float* __restrict__ ba1,
                                                   const float* __restrict__ Wa2,
                                                   const float* __restrict__ ba2,
                                                   float* __restrict__ wlog) {
  int tid = threadIdx.x;
  int j = tid & 63, w = tid >> 6;
  int bn = blockIdx.x * 4 + w;
  const float* f = f3 + (size_t)bn * 256;
  float acc = 0.f;
  for (int cidx = 0; cidx < 256; ++cidx) acc = fmaf(f[cidx], Wa1[cidx * 64 + j], acc);
  acc += ba1[j];
  acc = fmaxf(acc, 0.f);
  float v = acc * Wa2[j];
  for (int off = 32; off >= 1; off >>= 1) v += __shfl_down(v, off);
  if (j == 0) wlog[bn] = v + ba2[0];
}

__global__ __launch_bounds__(256) void poolstat_kernel(const float* __restrict__ wlog,
                                                       float* __restrict__ rowstat) {
  __shared__ float red[256];
  int b = blockIdx.x, tid = threadIdx.x;
  const float* wl = wlog + (size_t)b * NN;
  float mx = -3.4e38f;
  for (int n = tid; n < NN; n += 256) mx = fmaxf(mx, wl[n]);
  red[tid] = mx; __syncthreads();
  for (int s = 128; s > 0; s >>= 1) { if (tid < s) red[tid] = fmaxf(red[tid], red[tid + s]); __syncthreads(); }
  mx = red[0]; __syncthreads();
  float se = 0.f;
  for (int n = tid; n < NN; n += 256) se += expf(wl[n] - mx);
  red[tid] = se; __syncthreads();
  for (int s = 128; s > 0; s >>= 1) { if (tid < s) red[tid] += red[tid + s]; __syncthreads(); }
  if (tid == 0) { rowstat[b * 2] = mx; rowstat[b * 2 + 1] = red[0]; }
}

__global__ __launch_bounds__(256) void pooled_kernel(const float* __restrict__ f3,
                                                     const float* __restrict__ wlog,
                                                     const float* __restrict__ rowstat,
                                                     float* __restrict__ pooled) {
  int b = blockIdx.y, chunk = blockIdx.x;
  int tid = threadIdx.x;
  float mx = rowstat[b * 2], inv = 1.0f / rowstat[b * 2 + 1];
  float acc = 0.f;
  int n0 = chunk * 1024;
  for (int n = n0; n < n0 + 1024; ++n) {
    float a = expf(wlog[(size_t)b * NN + n] - mx) * inv;
    acc = fmaf(f3[((size_t)b * NN + n) * 256 + tid], a, acc);
  }
  atomicAdd(&pooled[b * 256 + tid], acc);
}

__global__ __launch_bounds__(256) void final_kernel(const float* __restrict__ pooled,
                                                    const float* __restrict__ Wfc,
                                                    const float* __restrict__ bfc,
                                                    float* __restrict__ out) {
  int b = blockIdx.x, o = threadIdx.x;
  float acc = 0.f;
  for (int c = 0; c < 256; ++c) acc = fmaf(pooled[b * 256 + c], Wfc[c * 256 + o], acc);
  acc += bfc[o];
  out[b * 256 + o] = fmaxf(acc, 0.f);
}

// ---------------------------------------------------------------- launch
static constexpr size_t align256(size_t v) { return (v + 255) & ~(size_t)255; }

extern "C" void kernel_launch(void* const* d_in, const int* in_sizes, int n_in,
                              void* d_out, int out_size, void* d_ws, size_t ws_size,
                              hipStream_t stream) {
  const float* x    = (const float*)d_in[0];
  const float* W1   = (const float*)d_in[1];
  const float* g1   = (const float*)d_in[2];
  const float* b1   = (const float*)d_in[3];
  const float* W2   = (const float*)d_in[4];
  const float* g2   = (const float*)d_in[5];
  const float* b2   = (const float*)d_in[6];
  const float* Ws2a = (const float*)d_in[7];
  const float* bs2a = (const float*)d_in[8];
  const float* Ws2b = (const float*)d_in[9];
  const float* bs2b = (const float*)d_in[10];
  const float* W3   = (const float*)d_in[11];
  const float* g3   = (const float*)d_in[12];
  const float* b3   = (const float*)d_in[13];
  const float* Ws3a = (const float*)d_in[14];
  const float* bs3a = (const float*)d_in[15];
  const float* Ws3b = (const float*)d_in[16];
  const float* bs3b = (const float*)d_in[17];
  const float* Wa1  = (const float*)d_in[18];
  const float* ba1  = (const float*)d_in[19];
  const float* Wa2  = (const float*)d_in[20];
  const float* ba2  = (const float*)d_in[21];
  const float* Wfc  = (const float*)d_in[22];
  const float* bfc  = (const float*)d_in[23];
  float* out = (float*)d_out;

  char* ws = (char*)d_ws;
  size_t off = 0;
  auto take = [&](size_t bytes) { size_t o = off; off = align256(off + bytes); return o; };
  size_t o_nbr  = take((size_t)BB * NN * KP * 4);
  size_t o_f1   = take((size_t)BB * NN * 64 * 4);
  size_t o_f2   = take((size_t)BB * NN * 128 * 4);
  size_t o_f3   = take((size_t)BB * NN * 256 * 4);
  size_t o_U2   = take((size_t)BB * NN * 256 * 4);
  size_t o_UA2  = take((size_t)BB * NN * 128 * 4);
  size_t o_U3   = take((size_t)BB * NN * 512 * 4);
  size_t o_UA3  = take((size_t)BB * NN * 256 * 4);
  size_t o_P2m  = take(64 * 256 * 4);
  size_t o_P2a  = take(64 * 128 * 4);
  size_t o_P3m  = take(128 * 512 * 4);
  size_t o_P3a  = take(128 * 256 * 4);
  size_t o_st   = take(896 * 4);       // stats1(128) stats2(256) stats3(512)
  size_t o_wlog = take((size_t)BB * NN * 4);
  size_t o_rs   = take(16 * 4);
  size_t o_pool = take(BB * 256 * 4);

  int*   nbr   = (int*)(ws + o_nbr);
  float* f1    = (float*)(ws + o_f1);
  float* f2    = (float*)(ws + o_f2);
  float* f3    = (float*)(ws + o_f3);
  float* U2    = (float*)(ws + o_U2);
  float* UA2   = (float*)(ws + o_UA2);
  float* U3    = (float*)(ws + o_U3);
  float* UA3   = (float*)(ws + o_UA3);
  float* P2m   = (float*)(ws + o_P2m);
  float* P2a   = (float*)(ws + o_P2a);
  float* P3m   = (float*)(ws + o_P3m);
  float* P3a   = (float*)(ws + o_P3a);
  float* stats1 = (float*)(ws + o_st);
  float* stats2 = stats1 + 128;
  float* stats3 = stats2 + 256;
  float* wlog  = (float*)(ws + o_wlog);
  float* rowst = (float*)(ws + o_rs);
  float* pooled = (float*)(ws + o_pool);

  hipMemsetAsync(ws + o_st, 0, 896 * 4, stream);
  hipMemsetAsync(ws + o_pool, 0, BB * 256 * 4, stream);

  knn_kernel<<<dim3(NN / 128, BB), 128, 0, stream>>>(x, nbr);
  stats1_kernel<<<dim3(NN / 32, BB), 256, 0, stream>>>(x, nbr, W1, stats1);
  apply1_kernel<<<dim3(NN / 16, BB), 256, 0, stream>>>(x, nbr, W1, g1, b1, stats1, f1);

  pack_kernel<<<(64 * 256 + 255) / 256, 256, 0, stream>>>(W2, P2m, 64, 128);
  pack_kernel<<<(64 * 128 + 255) / 256, 256, 0, stream>>>(Ws2a, P2a, 64, 64);
  pack_kernel<<<(128 * 512 + 255) / 256, 256, 0, stream>>>(W3, P3m, 128, 256);
  pack_kernel<<<(128 * 256 + 255) / 256, 256, 0, stream>>>(Ws3a, P3a, 128, 128);

  gemm_kernel<64><<<dim3(256 / 64, (BB * NN) / 64), 256, 0, stream>>>(f1, P2m, U2, 256);
  gemm_kernel<64><<<dim3(128 / 64, (BB * NN) / 64), 256, 0, stream>>>(f1, P2a, UA2, 128);
  soft_stats_kernel<128><<<(BB * NN) / 64, 256, 0, stream>>>(U2, nbr, stats2);
  soft_apply_kernel<128, 64><<<BB * NN, 128, 0, stream>>>(U2, UA2, nbr, stats2, g2, b2,
                                                          bs2a, Ws2b, bs2b, f2);

  gemm_kernel<128><<<dim3(512 / 64, (BB * NN) / 64), 256, 0, stream>>>(f2, P3m, U3, 512);
  gemm_kernel<128><<<dim3(256 / 64, (BB * NN) / 64), 256, 0, stream>>>(f2, P3a, UA3, 256);
  soft_stats_kernel<256><<<(BB * NN) / 32, 256, 0, stream>>>(U3, nbr, stats3);
  soft_apply_kernel<256, 128><<<BB * NN, 256, 0, stream>>>(U3, UA3, nbr, stats3, g3, b3,
                                                           bs3a, Ws3b, bs3b, f3);

  wlog_kernel<<<(BB * NN) / 4, 256, 0, stream>>>(f3, Wa1, ba1, Wa2, ba2, wlog);
  poolstat_kernel<<<BB, 256, 0, stream>>>(wlog, rowst);
  pooled_kernel<<<dim3(4, BB), 256, 0, stream>>>(f3, wlog, rowst, pooled);
  final_kernel<<<BB, 256, 0, stream>>>(pooled, Wfc, bfc, out);
}

// Round 2
// 1253.215 us; speedup vs baseline: 1.1209x; 1.1209x over previous
//
#include <hip/hip_runtime.h>
#include <hip/hip_bf16.h>
#include <cstdint>

constexpr int BB = 8;
constexpr int NN = 4096;
constexpr int KN = 10;     // K neighbors used
constexpr int KP = 11;     // K+1 stored
constexpr float EPS_BN = 1e-5f;
constexpr float TAU_V = 0.2f;
constexpr float INV_CNT = 1.0f / (float)(BB * NN * KN);

// ---------------------------------------------------------------- KNN
// float4-packed LDS + 16-wide branch-free distance chunks + chunk-min skip.
__global__ __launch_bounds__(128) void knn_kernel(const float* __restrict__ x,
                                                  int* __restrict__ nbr) {
  __shared__ float4 pts[NN];  // 64 KB: (x,y,z,|p|^2)
  int b = blockIdx.y;
  int n = blockIdx.x * 128 + threadIdx.x;
  const float* xb = x + (size_t)b * NN * 5;
  for (int m = threadIdx.x; m < NN; m += 128) {
    float px = xb[m * 5 + 0], py = xb[m * 5 + 1], pz = xb[m * 5 + 2];
    pts[m] = make_float4(px, py, pz, px * px + py * py + pz * pz);
  }
  __syncthreads();
  float4 q = pts[n];
  float qx = q.x, qy = q.y, qz = q.z, qs = q.w;
  float bd[KP]; int bi[KP];
#pragma unroll
  for (int j = 0; j < KP; ++j) { bd[j] = 3.4e38f; bi[j] = 0; }
  constexpr int CH = 16;
  for (int m0 = 0; m0 < NN; m0 += CH) {
    float d[CH];
#pragma unroll
    for (int u = 0; u < CH; ++u) {
      float4 p = pts[m0 + u];
      // identical contraction to reference-matching form: (qs+sq[m]) - 2*dot
      d[u] = qs + p.w - 2.0f * (qx * p.x + qy * p.y + qz * p.z);
    }
    // tree min of the chunk
    float m8[8];
#pragma unroll
    for (int u = 0; u < 8; ++u) m8[u] = fminf(d[u], d[u + 8]);
#pragma unroll
    for (int u = 0; u < 4; ++u) m8[u] = fminf(m8[u], m8[u + 4]);
    float cmin = fminf(fminf(m8[0], m8[1]), fminf(m8[2], m8[3]));
    if (cmin < bd[KP - 1]) {
#pragma unroll
      for (int u = 0; u < CH; ++u) {
        float dv = d[u];
        if (dv < bd[KP - 1]) {
          bd[KP - 1] = dv; bi[KP - 1] = m0 + u;
#pragma unroll
          for (int j = KP - 1; j > 0; --j) {
            if (bd[j] < bd[j - 1]) {
              float td = bd[j]; bd[j] = bd[j - 1]; bd[j - 1] = td;
              int ti = bi[j]; bi[j] = bi[j - 1]; bi[j - 1] = ti;
            }
          }
        }
      }
    }
  }
  int* o = nbr + ((size_t)b * NN + n) * KP;
#pragma unroll
  for (int j = 0; j < KP; ++j) o[j] = bi[j];
}

// ---------------------------------------------------------------- layer1 stats
// e1 = [cg-ci(3), ci(3), ag-ai(2), ai(2)] ; y = e1 @ W1 (10x64)
__device__ inline void stage_e1(const float* __restrict__ x, const int* __restrict__ nbr,
                                float (*e1s)[10], int b, int n0, int nedges, int tid, int nthreads) {
  for (int e = tid; e < nedges; e += nthreads) {
    int p = e / KN, k = e - p * KN;
    int n = n0 + p;
    const float* xn = x + ((size_t)b * NN + n) * 5;
    int g = nbr[((size_t)b * NN + n) * KP + k];  // idx1 = first K entries (incl self)
    const float* xg = x + ((size_t)b * NN + g) * 5;
    float cx = xn[0], cy = xn[1], cz = xn[2], a0 = xn[3], a1 = xn[4];
    e1s[e][0] = xg[0] - cx; e1s[e][1] = xg[1] - cy; e1s[e][2] = xg[2] - cz;
    e1s[e][3] = cx;         e1s[e][4] = cy;         e1s[e][5] = cz;
    e1s[e][6] = xg[3] - a0; e1s[e][7] = xg[4] - a1;
    e1s[e][8] = a0;         e1s[e][9] = a1;
  }
}

__global__ __launch_bounds__(256) void stats1_kernel(const float* __restrict__ x,
                                                     const int* __restrict__ nbr,
                                                     const float* __restrict__ W1,
                                                     float* __restrict__ stats) {
  constexpr int PPB = 32;
  __shared__ float e1s[PPB * KN][10];
  __shared__ float W1s[10][64];
  __shared__ float red[256];
  int b = blockIdx.y;
  int n0 = blockIdx.x * PPB;
  int tid = threadIdx.x;
  for (int i = tid; i < 640; i += 256) W1s[i / 64][i % 64] = W1[i];
  stage_e1(x, nbr, e1s, b, n0, PPB * KN, tid, 256);
  __syncthreads();
  int c = tid & 63, lane = tid >> 6;
  float s = 0.f, ss = 0.f;
  for (int e = lane; e < PPB * KN; e += 4) {
    float y = 0.f;
#pragma unroll
    for (int i = 0; i < 10; ++i) y = fmaf(e1s[e][i], W1s[i][c], y);
    s += y; ss += y * y;
  }
  red[tid] = s; __syncthreads();
  float s4 = 0.f, ss4 = 0.f;
  if (lane == 0) s4 = red[c] + red[c + 64] + red[c + 128] + red[c + 192];
  __syncthreads();
  red[tid] = ss; __syncthreads();
  if (lane == 0) {
    ss4 = red[c] + red[c + 64] + red[c + 128] + red[c + 192];
    atomicAdd(&stats[c], s4);
    atomicAdd(&stats[64 + c], ss4);
  }
}

__global__ __launch_bounds__(256) void apply1_kernel(const float* __restrict__ x,
                                                     const int* __restrict__ nbr,
                                                     const float* __restrict__ W1,
                                                     const float* __restrict__ g1,
                                                     const float* __restrict__ b1,
                                                     const float* __restrict__ stats,
                                                     float* __restrict__ f1) {
  constexpr int PPB = 16;
  __shared__ float e1s[PPB * KN][10];
  __shared__ float W1s[10][64];
  int b = blockIdx.y;
  int n0 = blockIdx.x * PPB;
  int tid = threadIdx.x;
  for (int i = tid; i < 640; i += 256) W1s[i / 64][i % 64] = W1[i];
  stage_e1(x, nbr, e1s, b, n0, PPB * KN, tid, 256);
  __syncthreads();
  int c = tid & 63, pl = tid >> 6;
  float mean = stats[c] * INV_CNT;
  float var = stats[64 + c] * INV_CNT - mean * mean;
  float scale = g1[c] * rsqrtf(var + EPS_BN);
  float shift = b1[c] - mean * scale;
  for (int p = pl; p < PPB; p += 4) {
    float mx = 0.0f;  // relu outputs are >= 0
#pragma unroll
    for (int k = 0; k < KN; ++k) {
      float y = 0.f;
#pragma unroll
      for (int i = 0; i < 10; ++i) y = fmaf(e1s[p * KN + k][i], W1s[i][c], y);
      float h = scale * y + shift;
      mx = fmaxf(mx, h);
    }
    f1[((size_t)b * NN + n0 + p) * 64 + c] = mx;
  }
}

// ---------------------------------------------------------------- weight packing
// dst[k][j] for k<Kh, j<2*Nout:  j<Nout -> src[k][j]  (u part)
//                                j>=Nout -> src[Kh+k][j-Nout]-src[k][j-Nout] (d part)
__global__ void pack_kernel(const float* __restrict__ src, float* __restrict__ dst,
                            int Kh, int Nout) {
  int idx = blockIdx.x * 256 + threadIdx.x;
  int tot = Kh * 2 * Nout;
  if (idx >= tot) return;
  int k = idx / (2 * Nout);
  int j = idx - k * 2 * Nout;
  float v;
  if (j < Nout) v = src[k * Nout + j];
  else { int jj = j - Nout; v = src[(Kh + k) * Nout + jj] - src[k * Nout + jj]; }
  dst[idx] = v;
}

// ---------------------------------------------------------------- tiled SGEMM
// C[M x Nc] = A[M x Kd] @ P[Kd x Nc], row-major. M,Nc mult of 64, Kd of 16.
// A-tile stored k-major so both operand reads are single ds_read_b128.
template <int Kd>
__global__ __launch_bounds__(256) void gemm_kernel(const float* __restrict__ A,
                                                   const float* __restrict__ P,
                                                   float* __restrict__ C, int Nc) {
  __shared__ float As[16][68];  // 68: 16B-aligned pad, <=2-way write conflict (free)
  __shared__ float Bs[16][64];
  int tid = threadIdx.x;
  int tx = tid & 15, ty = tid >> 4;
  int r0 = blockIdx.y * 64, c0 = blockIdx.x * 64;
  float acc[4][4] = {};
  for (int k0 = 0; k0 < Kd; k0 += 16) {
    for (int e = tid; e < 1024; e += 256) {
      int r = e >> 4, kk = e & 15;
      As[kk][r] = A[(size_t)(r0 + r) * Kd + k0 + kk];
    }
    for (int e = tid; e < 1024; e += 256) {
      int kk = e >> 6, cc = e & 63;
      Bs[kk][cc] = P[(size_t)(k0 + kk) * Nc + c0 + cc];
    }
    __syncthreads();
#pragma unroll
    for (int kk = 0; kk < 16; ++kk) {
      float4 av = *(const float4*)&As[kk][ty * 4];
      float4 bv = *(const float4*)&Bs[kk][tx * 4];
      float a[4] = {av.x, av.y, av.z, av.w};
      float bb[4] = {bv.x, bv.y, bv.z, bv.w};
#pragma unroll
      for (int i = 0; i < 4; ++i)
#pragma unroll
        for (int j = 0; j < 4; ++j) acc[i][j] = fmaf(a[i], bb[j], acc[i][j]);
    }
    __syncthreads();
  }
#pragma unroll
  for (int i = 0; i < 4; ++i) {
    float4 ov = make_float4(acc[i][0], acc[i][1], acc[i][2], acc[i][3]);
    *(float4*)&C[(size_t)(r0 + ty * 4 + i) * Nc + c0 + tx * 4] = ov;
  }
}

// ---------------------------------------------------------------- soft-edge stats
// U layout per point: [u(C) | d(C)] ; y_{n,k,c} = U[idx_k][c] + U[n][C+c]
template <int C>
__global__ __launch_bounds__(256) void soft_stats_kernel(const float* __restrict__ U,
                                                         const int* __restrict__ nbr,
                                                         float* __restrict__ stats) {
  constexpr int LANES = 256 / C;
  constexpr int PPB = (C == 128) ? 64 : 32;
  __shared__ float red[256];
  int tid = threadIdx.x;
  int c = tid % C;
  int lane = tid / C;
  int bn0 = blockIdx.x * PPB;
  float s = 0.f, ss = 0.f;
  for (int p = lane; p < PPB; p += LANES) {
    int bn = bn0 + p;
    int b = bn >> 12;
    float d = U[(size_t)bn * (2 * C) + C + c];
    const int* ix = nbr + (size_t)bn * KP;
#pragma unroll
    for (int k = 1; k <= KN; ++k) {  // idx = entries 1..K (excl self)
      int row = ix[k];
      float y = U[((size_t)(b << 12) + row) * (2 * C) + c] + d;
      s += y; ss += y * y;
    }
  }
  if (LANES == 2) {
    red[tid] = s; __syncthreads();
    float s2 = 0.f;
    if (tid < C) s2 = red[tid] + red[tid + C];
    __syncthreads();
    red[tid] = ss; __syncthreads();
    if (tid < C) {
      float ss2 = red[tid] + red[tid + C];
      atomicAdd(&stats[c], s2);
      atomicAdd(&stats[C + c], ss2);
    }
  } else {
    atomicAdd(&stats[c], s);
    atomicAdd(&stats[C + c], ss);
  }
}

// ---------------------------------------------------------------- soft-edge apply
template <int C, int CA>
__global__ __launch_bounds__(C) void soft_apply_kernel(const float* __restrict__ U,
                                                       const float* __restrict__ UA,
                                                       const int* __restrict__ nbr,
                                                       const float* __restrict__ stats,
                                                       const float* __restrict__ gbn,
                                                       const float* __restrict__ bbn,
                                                       const float* __restrict__ ba,
                                                       const float* __restrict__ Wb,
                                                       const float* __restrict__ bbv,
                                                       float* __restrict__ fout) {
  __shared__ int ixs[KN];
  __shared__ float logits[KN];
  __shared__ float parts[KN][2];
  int tid = threadIdx.x;
  int bn = blockIdx.x;
  int b = bn >> 12;
  if (tid < KN) ixs[tid] = nbr[(size_t)bn * KP + 1 + tid];
  __syncthreads();
  float pv[KN];
  if (tid < CA) {
    float da = UA[(size_t)bn * (2 * CA) + CA + tid] + ba[tid];
    float wbj = Wb[tid];
#pragma unroll
    for (int k = 0; k < KN; ++k) {
      int row = ixs[k];
      float h = UA[((size_t)(b << 12) + row) * (2 * CA) + tid] + da;
      h = fmaxf(h, 0.f);
      pv[k] = h * wbj;
    }
  } else {
#pragma unroll
    for (int k = 0; k < KN; ++k) pv[k] = 0.f;
  }
#pragma unroll
  for (int k = 0; k < KN; ++k) {
    float v = pv[k];
    for (int off = 32; off >= 1; off >>= 1) v += __shfl_down(v, off);
    if ((tid & 63) == 0 && tid < CA) parts[k][tid >> 6] = v;
  }
  __syncthreads();
  if (tid == 0) {
    float bsv = bbv[0];
#pragma unroll
    for (int k = 0; k < KN; ++k) {
      float l = parts[k][0];
      if (CA == 128) l += parts[k][1];
      logits[k] = (l + bsv) * (1.0f / TAU_V);
    }
  }
  __syncthreads();
  // redundant per-thread softmax over K
  float lg[KN], mx = -3.4e38f;
#pragma unroll
  for (int k = 0; k < KN; ++k) { lg[k] = logits[k]; mx = fmaxf(mx, lg[k]); }
  float se = 0.f;
#pragma unroll
  for (int k = 0; k < KN; ++k) { lg[k] = expf(lg[k] - mx); se += lg[k]; }
  float inv = 1.0f / se;
  int c = tid;
  float mean = stats[c] * INV_CNT;
  float var = stats[C + c] * INV_CNT - mean * mean;
  float scale = gbn[c] * rsqrtf(var + EPS_BN);
  float shift = bbn[c] - mean * scale;
  float d = U[(size_t)bn * (2 * C) + C + c];
  float acc = 0.f;
#pragma unroll
  for (int k = 0; k < KN; ++k) {
    int row = ixs[k];
    float y = U[((size_t)(b << 12) + row) * (2 * C) + c] + d;
    float h = fmaxf(scale * y + shift, 0.f);
    acc += h * lg[k];
  }
  fout[(size_t)bn * C + c] = acc * inv;
}

// ---------------------------------------------------------------- global attention pool
__global__ __launch_bounds__(256) void wlog_kernel(const float* __restrict__ f3,
                                                   const float* __restrict__ Wa1,
                                                   const float* __restrict__ ba1,
                                                   const float* __restrict__ Wa2,
                                                   const float* __restrict__ ba2,
                                                   float* __restrict__ wlog) {
  int tid = threadIdx.x;
  int j = tid & 63, w = tid >> 6;
  int bn = blockIdx.x * 4 + w;
  const float* f = f3 + (size_t)bn * 256;
  float acc = 0.f;
  for (int cidx = 0; cidx < 256; ++cidx) acc = fmaf(f[cidx], Wa1[cidx * 64 + j], acc);
  acc += ba1[j];
  acc = fmaxf(acc, 0.f);
  float v = acc * Wa2[j];
  for (int off = 32; off >= 1; off >>= 1) v += __shfl_down(v, off);
  if (j == 0) wlog[bn] = v + ba2[0];
}

__global__ __launch_bounds__(256) void poolstat_kernel(const float* __restrict__ wlog,
                                                       float* __restrict__ rowstat) {
  __shared__ float red[256];
  int b = blockIdx.x, tid = threadIdx.x;
  const float* wl = wlog + (size_t)b * NN;
  float mx = -3.4e38f;
  for (int n = tid; n < NN; n += 256) mx = fmaxf(mx, wl[n]);
  red[tid] = mx; __syncthreads();
  for (int s = 128; s > 0; s >>= 1) { if (tid < s) red[tid] = fmaxf(red[tid], red[tid + s]); __syncthreads(); }
  mx = red[0]; __syncthreads();
  float se = 0.f;
  for (int n = tid; n < NN; n += 256) se += expf(wl[n] - mx);
  red[tid] = se; __syncthreads();
  for (int s = 128; s > 0; s >>= 1) { if (tid < s) red[tid] += red[tid + s]; __syncthreads(); }
  if (tid == 0) { rowstat[b * 2] = mx; rowstat[b * 2 + 1] = red[0]; }
}

__global__ __launch_bounds__(256) void pooled_kernel(const float* __restrict__ f3,
                                                     const float* __restrict__ wlog,
                                                     const float* __restrict__ rowstat,
                                                     float* __restrict__ pooled) {
  int b = blockIdx.y, chunk = blockIdx.x;
  int tid = threadIdx.x;
  float mx = rowstat[b * 2], inv = 1.0f / rowstat[b * 2 + 1];
  float acc = 0.f;
  int n0 = chunk * 1024;
  for (int n = n0; n < n0 + 1024; ++n) {
    float a = expf(wlog[(size_t)b * NN + n] - mx) * inv;
    acc = fmaf(f3[((size_t)b * NN + n) * 256 + tid], a, acc);
  }
  atomicAdd(&pooled[b * 256 + tid], acc);
}

__global__ __launch_bounds__(256) void final_kernel(const float* __restrict__ pooled,
                                                    const float* __restrict__ Wfc,
                                                    const float* __restrict__ bfc,
                                                    float* __restrict__ out) {
  int b = blockIdx.x, o = threadIdx.x;
  float acc = 0.f;
  for (int c = 0; c < 256; ++c) acc = fmaf(pooled[b * 256 + c], Wfc[c * 256 + o], acc);
  acc += bfc[o];
  out[b * 256 + o] = fmaxf(acc, 0.f);
}

// ---------------------------------------------------------------- launch
static constexpr size_t align256(size_t v) { return (v + 255) & ~(size_t)255; }

extern "C" void kernel_launch(void* const* d_in, const int* in_sizes, int n_in,
                              void* d_out, int out_size, void* d_ws, size_t ws_size,
                              hipStream_t stream) {
  const float* x    = (const float*)d_in[0];
  const float* W1   = (const float*)d_in[1];
  const float* g1   = (const float*)d_in[2];
  const float* b1   = (const float*)d_in[3];
  const float* W2   = (const float*)d_in[4];
  const float* g2   = (const float*)d_in[5];
  const float* b2   = (const float*)d_in[6];
  const float* Ws2a = (const float*)d_in[7];
  const float* bs2a = (const float*)d_in[8];
  const float* Ws2b = (const float*)d_in[9];
  const float* bs2b = (const float*)d_in[10];
  const float* W3   = (const float*)d_in[11];
  const float* g3   = (const float*)d_in[12];
  const float* b3   = (const float*)d_in[13];
  const float* Ws3a = (const float*)d_in[14];
  const float* bs3a = (const float*)d_in[15];
  const float* Ws3b = (const float*)d_in[16];
  const float* bs3b = (const float*)d_in[17];
  const float* Wa1  = (const float*)d_in[18];
  const float* ba1  = (const float*)d_in[19];
  const float* Wa2  = (const float*)d_in[20];
  const float* ba2  = (const float*)d_in[21];
  const float* Wfc  = (const float*)d_in[22];
  const float* bfc  = (const float*)d_in[23];
  float* out = (float*)d_out;

  char* ws = (char*)d_ws;
  size_t off = 0;
  auto take = [&](size_t bytes) { size_t o = off; off = align256(off + bytes); return o; };
  size_t o_nbr  = take((size_t)BB * NN * KP * 4);
  size_t o_f1   = take((size_t)BB * NN * 64 * 4);
  size_t o_f2   = take((size_t)BB * NN * 128 * 4);
  size_t o_f3   = take((size_t)BB * NN * 256 * 4);
  size_t o_U2   = take((size_t)BB * NN * 256 * 4);
  size_t o_UA2  = take((size_t)BB * NN * 128 * 4);
  size_t o_U3   = take((size_t)BB * NN * 512 * 4);
  size_t o_UA3  = take((size_t)BB * NN * 256 * 4);
  size_t o_P2m  = take(64 * 256 * 4);
  size_t o_P2a  = take(64 * 128 * 4);
  size_t o_P3m  = take(128 * 512 * 4);
  size_t o_P3a  = take(128 * 256 * 4);
  size_t o_st   = take(896 * 4);       // stats1(128) stats2(256) stats3(512)
  size_t o_wlog = take((size_t)BB * NN * 4);
  size_t o_rs   = take(16 * 4);
  size_t o_pool = take(BB * 256 * 4);

  int*   nbr   = (int*)(ws + o_nbr);
  float* f1    = (float*)(ws + o_f1);
  float* f2    = (float*)(ws + o_f2);
  float* f3    = (float*)(ws + o_f3);
  float* U2    = (float*)(ws + o_U2);
  float* UA2   = (float*)(ws + o_UA2);
  float* U3    = (float*)(ws + o_U3);
  float* UA3   = (float*)(ws + o_UA3);
  float* P2m   = (float*)(ws + o_P2m);
  float* P2a   = (float*)(ws + o_P2a);
  float* P3m   = (float*)(ws + o_P3m);
  float* P3a   = (float*)(ws + o_P3a);
  float* stats1 = (float*)(ws + o_st);
  float* stats2 = stats1 + 128;
  float* stats3 = stats2 + 256;
  float* wlog  = (float*)(ws + o_wlog);
  float* rowst = (float*)(ws + o_rs);
  float* pooled = (float*)(ws + o_pool);

  hipMemsetAsync(ws + o_st, 0, 896 * 4, stream);
  hipMemsetAsync(ws + o_pool, 0, BB * 256 * 4, stream);

  knn_kernel<<<dim3(NN / 128, BB), 128, 0, stream>>>(x, nbr);
  stats1_kernel<<<dim3(NN / 32, BB), 256, 0, stream>>>(x, nbr, W1, stats1);
  apply1_kernel<<<dim3(NN / 16, BB), 256, 0, stream>>>(x, nbr, W1, g1, b1, stats1, f1);

  pack_kernel<<<(64 * 256 + 255) / 256, 256, 0, stream>>>(W2, P2m, 64, 128);
  pack_kernel<<<(64 * 128 + 255) / 256, 256, 0, stream>>>(Ws2a, P2a, 64, 64);
  pack_kernel<<<(128 * 512 + 255) / 256, 256, 0, stream>>>(W3, P3m, 128, 256);
  pack_kernel<<<(128 * 256 + 255) / 256, 256, 0, stream>>>(Ws3a, P3a, 128, 128);

  gemm_kernel<64><<<dim3(256 / 64, (BB * NN) / 64), 256, 0, stream>>>(f1, P2m, U2, 256);
  gemm_kernel<64><<<dim3(128 / 64, (BB * NN) / 64), 256, 0, stream>>>(f1, P2a, UA2, 128);
  soft_stats_kernel<128><<<(BB * NN) / 64, 256, 0, stream>>>(U2, nbr, stats2);
  soft_apply_kernel<128, 64><<<BB * NN, 128, 0, stream>>>(U2, UA2, nbr, stats2, g2, b2,
                                                          bs2a, Ws2b, bs2b, f2);

  gemm_kernel<128><<<dim3(512 / 64, (BB * NN) / 64), 256, 0, stream>>>(f2, P3m, U3, 512);
  gemm_kernel<128><<<dim3(256 / 64, (BB * NN) / 64), 256, 0, stream>>>(f2, P3a, UA3, 256);
  soft_stats_kernel<256><<<(BB * NN) / 32, 256, 0, stream>>>(U3, nbr, stats3);
  soft_apply_kernel<256, 128><<<BB * NN, 256, 0, stream>>>(U3, UA3, nbr, stats3, g3, b3,
                                                           bs3a, Ws3b, bs3b, f3);

  wlog_kernel<<<(BB * NN) / 4, 256, 0, stream>>>(f3, Wa1, ba1, Wa2, ba2, wlog);
  poolstat_kernel<<<BB, 256, 0, stream>>>(wlog, rowst);
  pooled_kernel<<<dim3(4, BB), 256, 0, stream>>>(f3, wlog, rowst, pooled);
  final_kernel<<<BB, 256, 0, stream>>>(pooled, Wfc, bfc, out);
}

// Round 6
// 1154.368 us; speedup vs baseline: 1.2169x; 1.0856x over previous
//
#include <hip/hip_runtime.h>
#include <hip/hip_bf16.h>
#include <cstdint>

constexpr int BB = 8;
constexpr int NN = 4096;
constexpr int KN = 10;     // K neighbors used
constexpr int KP = 11;     // K+1 stored
constexpr float EPS_BN = 1e-5f;
constexpr float TAU_V = 0.2f;
constexpr float INV_CNT = 1.0f / (float)(BB * NN * KN);

// ---------------------------------------------------------------- KNN
// 512 threads: 128 queries x 4 candidate chunks (1024 each). Per-thread
// top-11 insertion sort -> LDS -> 4-way stable merge. 8 waves/CU.
__global__ __launch_bounds__(512) void knn_kernel(const float* __restrict__ x,
                                                  int* __restrict__ nbr) {
  __shared__ float4 pts[NN];          // 64 KB: (x,y,z,|p|^2)
  __shared__ int2 mrg[128][4][KP];    // 44 KB: per-chunk sorted (d_bits, idx)
  int b = blockIdx.y;
  int tid = threadIdx.x;
  int s = tid >> 7;          // candidate chunk 0..3
  int q = tid & 127;         // query within block
  int n = blockIdx.x * 128 + q;
  const float* xb = x + (size_t)b * NN * 5;
  for (int m = tid; m < NN; m += 512) {
    float px = xb[m * 5 + 0], py = xb[m * 5 + 1], pz = xb[m * 5 + 2];
    pts[m] = make_float4(px, py, pz, px * px + py * py + pz * pz);
  }
  __syncthreads();
  float4 qv = pts[n];
  float qx = qv.x, qy = qv.y, qz = qv.z, qs = qv.w;
  float bd[KP]; int bi[KP];
#pragma unroll
  for (int j = 0; j < KP; ++j) { bd[j] = 3.4e38f; bi[j] = 0; }
  constexpr int CH = 16;
  int m_begin = s * (NN / 4), m_end = m_begin + NN / 4;
  for (int m0 = m_begin; m0 < m_end; m0 += CH) {
    float d[CH];
#pragma unroll
    for (int u = 0; u < CH; ++u) {
      float4 p = pts[m0 + u];
      // identical contraction to reference-matching form: (qs+sq[m]) - 2*dot
      d[u] = qs + p.w - 2.0f * (qx * p.x + qy * p.y + qz * p.z);
    }
    float m8[8];
#pragma unroll
    for (int u = 0; u < 8; ++u) m8[u] = fminf(d[u], d[u + 8]);
#pragma unroll
    for (int u = 0; u < 4; ++u) m8[u] = fminf(m8[u], m8[u + 4]);
    float cmin = fminf(fminf(m8[0], m8[1]), fminf(m8[2], m8[3]));
    if (cmin < bd[KP - 1]) {
#pragma unroll
      for (int u = 0; u < CH; ++u) {
        float dv = d[u];
        if (dv < bd[KP - 1]) {
          bd[KP - 1] = dv; bi[KP - 1] = m0 + u;
#pragma unroll
          for (int j = KP - 1; j > 0; --j) {
            if (bd[j] < bd[j - 1]) {
              float td = bd[j]; bd[j] = bd[j - 1]; bd[j - 1] = td;
              int ti = bi[j]; bi[j] = bi[j - 1]; bi[j - 1] = ti;
            }
          }
        }
      }
    }
  }
#pragma unroll
  for (int j = 0; j < KP; ++j)
    mrg[q][s][j] = make_int2(__float_as_int(bd[j]), bi[j]);
  __syncthreads();
  if (tid < 128) {
    // stable 4-way merge; chunk index ranges are ordered by s, and scan order
    // s=0..3 with strict < preserves lowest-index-wins on distance ties.
    unsigned ptrs = 0;  // four 8-bit list heads packed (avoids scratch arrays)
    int* o = nbr + ((size_t)b * NN + blockIdx.x * 128 + tid) * KP;
#pragma unroll
    for (int j = 0; j < KP; ++j) {
      float bestd = 3.5e38f; int besti = 0, bests = 0;
#pragma unroll
      for (int ss = 0; ss < 4; ++ss) {
        int p = (ptrs >> (8 * ss)) & 0xff;
        int2 v = mrg[tid][ss][p];
        float dv = __int_as_float(v.x);
        if (dv < bestd) { bestd = dv; besti = v.y; bests = ss; }
      }
      o[j] = besti;
      ptrs += (1u << (8 * bests));
    }
  }
}

// ---------------------------------------------------------------- layer1 stats
// e1 = [cg-ci(3), ci(3), ag-ai(2), ai(2)] ; y = e1 @ W1 (10x64)
__device__ inline void stage_e1(const float* __restrict__ x, const int* __restrict__ nbr,
                                float (*e1s)[10], int b, int n0, int nedges, int tid, int nthreads) {
  for (int e = tid; e < nedges; e += nthreads) {
    int p = e / KN, k = e - p * KN;
    int n = n0 + p;
    const float* xn = x + ((size_t)b * NN + n) * 5;
    int g = nbr[((size_t)b * NN + n) * KP + k];  // idx1 = first K entries (incl self)
    const float* xg = x + ((size_t)b * NN + g) * 5;
    float cx = xn[0], cy = xn[1], cz = xn[2], a0 = xn[3], a1 = xn[4];
    e1s[e][0] = xg[0] - cx; e1s[e][1] = xg[1] - cy; e1s[e][2] = xg[2] - cz;
    e1s[e][3] = cx;         e1s[e][4] = cy;         e1s[e][5] = cz;
    e1s[e][6] = xg[3] - a0; e1s[e][7] = xg[4] - a1;
    e1s[e][8] = a0;         e1s[e][9] = a1;
  }
}

__global__ __launch_bounds__(256) void stats1_kernel(const float* __restrict__ x,
                                                     const int* __restrict__ nbr,
                                                     const float* __restrict__ W1,
                                                     float* __restrict__ stats) {
  constexpr int PPB = 32;
  __shared__ float e1s[PPB * KN][10];
  __shared__ float W1s[10][64];
  __shared__ float red[256];
  int b = blockIdx.y;
  int n0 = blockIdx.x * PPB;
  int tid = threadIdx.x;
  for (int i = tid; i < 640; i += 256) W1s[i / 64][i % 64] = W1[i];
  stage_e1(x, nbr, e1s, b, n0, PPB * KN, tid, 256);
  __syncthreads();
  int c = tid & 63, lane = tid >> 6;
  float s = 0.f, ss = 0.f;
  for (int e = lane; e < PPB * KN; e += 4) {
    float y = 0.f;
#pragma unroll
    for (int i = 0; i < 10; ++i) y = fmaf(e1s[e][i], W1s[i][c], y);
    s += y; ss += y * y;
  }
  red[tid] = s; __syncthreads();
  float s4 = 0.f, ss4 = 0.f;
  if (lane == 0) s4 = red[c] + red[c + 64] + red[c + 128] + red[c + 192];
  __syncthreads();
  red[tid] = ss; __syncthreads();
  if (lane == 0) {
    ss4 = red[c] + red[c + 64] + red[c + 128] + red[c + 192];
    atomicAdd(&stats[c], s4);
    atomicAdd(&stats[64 + c], ss4);
  }
}

__global__ __launch_bounds__(256) void apply1_kernel(const float* __restrict__ x,
                                                     const int* __restrict__ nbr,
                                                     const float* __restrict__ W1,
                                                     const float* __restrict__ g1,
                                                     const float* __restrict__ b1,
                                                     const float* __restrict__ stats,
                                                     float* __restrict__ f1) {
  constexpr int PPB = 16;
  __shared__ float e1s[PPB * KN][10];
  __shared__ float W1s[10][64];
  int b = blockIdx.y;
  int n0 = blockIdx.x * PPB;
  int tid = threadIdx.x;
  for (int i = tid; i < 640; i += 256) W1s[i / 64][i % 64] = W1[i];
  stage_e1(x, nbr, e1s, b, n0, PPB * KN, tid, 256);
  __syncthreads();
  int c = tid & 63, pl = tid >> 6;
  float mean = stats[c] * INV_CNT;
  float var = stats[64 + c] * INV_CNT - mean * mean;
  float scale = g1[c] * rsqrtf(var + EPS_BN);
  float shift = b1[c] - mean * scale;
  for (int p = pl; p < PPB; p += 4) {
    float mx = 0.0f;  // relu outputs are >= 0
#pragma unroll
    for (int k = 0; k < KN; ++k) {
      float y = 0.f;
#pragma unroll
      for (int i = 0; i < 10; ++i) y = fmaf(e1s[p * KN + k][i], W1s[i][c], y);
      float h = scale * y + shift;
      mx = fmaxf(mx, h);
    }
    f1[((size_t)b * NN + n0 + p) * 64 + c] = mx;
  }
}

// ---------------------------------------------------------------- weight packing
// dst[k][j] for k<Kh, j<2*Nout:  j<Nout -> src[k][j]  (u part)
//                                j>=Nout -> src[Kh+k][j-Nout]-src[k][j-Nout] (d part)
__global__ void pack_kernel(const float* __restrict__ src, float* __restrict__ dst,
                            int Kh, int Nout) {
  int idx = blockIdx.x * 256 + threadIdx.x;
  int tot = Kh * 2 * Nout;
  if (idx >= tot) return;
  int k = idx / (2 * Nout);
  int j = idx - k * 2 * Nout;
  float v;
  if (j < Nout) v = src[k * Nout + j];
  else { int jj = j - Nout; v = src[(Kh + k) * Nout + jj] - src[k * Nout + jj]; }
  dst[idx] = v;
}

// ---------------------------------------------------------------- tiled SGEMM
// C[M x Nc] = A[M x Kd] @ P[Kd x Nc], row-major. 128x128 tile, 256 threads,
// 8x8 acc in 2x2 split sub-tiles (rows ty*4/+64, cols tx*4/+64): all LDS
// reads stride-4 float4 -> <=2-way conflicts (free); 64 FMA per 4 ds_read_b128.
template <int Kd>
__global__ __launch_bounds__(256) void gemm128_kernel(const float* __restrict__ A,
                                                      const float* __restrict__ P,
                                                      float* __restrict__ C, int Nc) {
  __shared__ float As[16][132];  // k-major, pad 132: staging write 2-way (free)
  __shared__ float Bs[16][128];
  int tid = threadIdx.x;
  int tx = tid & 15, ty = tid >> 4;
  int r0 = blockIdx.y * 128, c0 = blockIdx.x * 128;
  float acc[8][8] = {};
  for (int k0 = 0; k0 < Kd; k0 += 16) {
    // stage A: 128 rows x 16 k; thread e -> row e>>2, k-quad (e&3)*4
    for (int e = tid; e < 512; e += 256) {
      int r = e >> 2, kq = (e & 3) * 4;
      float4 v = *(const float4*)&A[(size_t)(r0 + r) * Kd + k0 + kq];
      As[kq + 0][r] = v.x; As[kq + 1][r] = v.y; As[kq + 2][r] = v.z; As[kq + 3][r] = v.w;
    }
    // stage B: 16 k-rows x 128 cols
    for (int e = tid; e < 512; e += 256) {
      int kk = e >> 5, cc = (e & 31) * 4;
      *(float4*)&Bs[kk][cc] = *(const float4*)&P[(size_t)(k0 + kk) * Nc + c0 + cc];
    }
    __syncthreads();
#pragma unroll
    for (int kk = 0; kk < 16; ++kk) {
      float4 a0 = *(const float4*)&As[kk][ty * 4];
      float4 a1 = *(const float4*)&As[kk][64 + ty * 4];
      float4 b0 = *(const float4*)&Bs[kk][tx * 4];
      float4 b1 = *(const float4*)&Bs[kk][64 + tx * 4];
      float a[8] = {a0.x, a0.y, a0.z, a0.w, a1.x, a1.y, a1.z, a1.w};
      float bb[8] = {b0.x, b0.y, b0.z, b0.w, b1.x, b1.y, b1.z, b1.w};
#pragma unroll
      for (int i = 0; i < 8; ++i)
#pragma unroll
        for (int j = 0; j < 8; ++j) acc[i][j] = fmaf(a[i], bb[j], acc[i][j]);
    }
    __syncthreads();
  }
#pragma unroll
  for (int i = 0; i < 8; ++i) {
    int r = r0 + ((i < 4) ? (ty * 4 + i) : (64 + ty * 4 + i - 4));
    float4 lo = make_float4(acc[i][0], acc[i][1], acc[i][2], acc[i][3]);
    float4 hi = make_float4(acc[i][4], acc[i][5], acc[i][6], acc[i][7]);
    *(float4*)&C[(size_t)r * Nc + c0 + tx * 4] = lo;
    *(float4*)&C[(size_t)r * Nc + c0 + 64 + tx * 4] = hi;
  }
}

// ---------------------------------------------------------------- soft-edge stats
// U layout per point: [u(C) | d(C)] ; y_{n,k,c} = U[idx_k][c] + U[n][C+c]
template <int C>
__global__ __launch_bounds__(256) void soft_stats_kernel(const float* __restrict__ U,
                                                         const int* __restrict__ nbr,
                                                         float* __restrict__ stats) {
  constexpr int LANES = 256 / C;
  constexpr int PPB = (C == 128) ? 64 : 32;
  __shared__ float red[256];
  int tid = threadIdx.x;
  int c = tid % C;
  int lane = tid / C;
  int bn0 = blockIdx.x * PPB;
  float s = 0.f, ss = 0.f;
  for (int p = lane; p < PPB; p += LANES) {
    int bn = bn0 + p;
    int b = bn >> 12;
    float d = U[(size_t)bn * (2 * C) + C + c];
    const int* ix = nbr + (size_t)bn * KP;
#pragma unroll
    for (int k = 1; k <= KN; ++k) {  // idx = entries 1..K (excl self)
      int row = ix[k];
      float y = U[((size_t)(b << 12) + row) * (2 * C) + c] + d;
      s += y; ss += y * y;
    }
  }
  if (LANES == 2) {
    red[tid] = s; __syncthreads();
    float s2 = 0.f;
    if (tid < C) s2 = red[tid] + red[tid + C];
    __syncthreads();
    red[tid] = ss; __syncthreads();
    if (tid < C) {
      float ss2 = red[tid] + red[tid + C];
      atomicAdd(&stats[c], s2);
      atomicAdd(&stats[C + c], ss2);
    }
  } else {
    atomicAdd(&stats[c], s);
    atomicAdd(&stats[C + c], ss);
  }
}

// ---------------------------------------------------------------- soft-edge apply
template <int C, int CA>
__global__ __launch_bounds__(C) void soft_apply_kernel(const float* __restrict__ U,
                                                       const float* __restrict__ UA,
                                                       const int* __restrict__ nbr,
                                                       const float* __restrict__ stats,
                                                       const float* __restrict__ gbn,
                                                       const float* __restrict__ bbn,
                                                       const float* __restrict__ ba,
                                                       const float* __restrict__ Wb,
                                                       const float* __restrict__ bbv,
                                                       float* __restrict__ fout) {
  __shared__ int ixs[KN];
  __shared__ float logits[KN];
  __shared__ float parts[KN][2];
  int tid = threadIdx.x;
  int bn = blockIdx.x;
  int b = bn >> 12;
  if (tid < KN) ixs[tid] = nbr[(size_t)bn * KP + 1 + tid];
  __syncthreads();
  float pv[KN];
  if (tid < CA) {
    float da = UA[(size_t)bn * (2 * CA) + CA + tid] + ba[tid];
    float wbj = Wb[tid];
#pragma unroll
    for (int k = 0; k < KN; ++k) {
      int row = ixs[k];
      float h = UA[((size_t)(b << 12) + row) * (2 * CA) + tid] + da;
      h = fmaxf(h, 0.f);
      pv[k] = h * wbj;
    }
  } else {
#pragma unroll
    for (int k = 0; k < KN; ++k) pv[k] = 0.f;
  }
#pragma unroll
  for (int k = 0; k < KN; ++k) {
    float v = pv[k];
    for (int off = 32; off >= 1; off >>= 1) v += __shfl_down(v, off);
    if ((tid & 63) == 0 && tid < CA) parts[k][tid >> 6] = v;
  }
  __syncthreads();
  if (tid == 0) {
    float bsv = bbv[0];
#pragma unroll
    for (int k = 0; k < KN; ++k) {
      float l = parts[k][0];
      if (CA == 128) l += parts[k][1];
      logits[k] = (l + bsv) * (1.0f / TAU_V);
    }
  }
  __syncthreads();
  // redundant per-thread softmax over K
  float lg[KN], mx = -3.4e38f;
#pragma unroll
  for (int k = 0; k < KN; ++k) { lg[k] = logits[k]; mx = fmaxf(mx, lg[k]); }
  float se = 0.f;
#pragma unroll
  for (int k = 0; k < KN; ++k) { lg[k] = expf(lg[k] - mx); se += lg[k]; }
  float inv = 1.0f / se;
  int c = tid;
  float mean = stats[c] * INV_CNT;
  float var = stats[C + c] * INV_CNT - mean * mean;
  float scale = gbn[c] * rsqrtf(var + EPS_BN);
  float shift = bbn[c] - mean * scale;
  float d = U[(size_t)bn * (2 * C) + C + c];
  float acc = 0.f;
#pragma unroll
  for (int k = 0; k < KN; ++k) {
    int row = ixs[k];
    float y = U[((size_t)(b << 12) + row) * (2 * C) + c] + d;
    float h = fmaxf(scale * y + shift, 0.f);
    acc += h * lg[k];
  }
  fout[(size_t)bn * C + c] = acc * inv;
}

// ---------------------------------------------------------------- global attention pool
__global__ __launch_bounds__(256) void wlog_kernel(const float* __restrict__ f3,
                                                   const float* __restrict__ Wa1,
                                                   const float* __restrict__ ba1,
                                                   const float* __restrict__ Wa2,
                                                   const float* __restrict__ ba2,
                                                   float* __restrict__ wlog) {
  int tid = threadIdx.x;
  int j = tid & 63, w = tid >> 6;
  int bn = blockIdx.x * 4 + w;
  const float* f = f3 + (size_t)bn * 256;
  float acc = 0.f;
  for (int cidx = 0; cidx < 256; ++cidx) acc = fmaf(f[cidx], Wa1[cidx * 64 + j], acc);
  acc += ba1[j];
  acc = fmaxf(acc, 0.f);
  float v = acc * Wa2[j];
  for (int off = 32; off >= 1; off >>= 1) v += __shfl_down(v, off);
  if (j == 0) wlog[bn] = v + ba2[0];
}

__global__ __launch_bounds__(256) void poolstat_kernel(const float* __restrict__ wlog,
                                                       float* __restrict__ rowstat) {
  __shared__ float red[256];
  int b = blockIdx.x, tid = threadIdx.x;
  const float* wl = wlog + (size_t)b * NN;
  float mx = -3.4e38f;
  for (int n = tid; n < NN; n += 256) mx = fmaxf(mx, wl[n]);
  red[tid] = mx; __syncthreads();
  for (int s = 128; s > 0; s >>= 1) { if (tid < s) red[tid] = fmaxf(red[tid], red[tid + s]); __syncthreads(); }
  mx = red[0]; __syncthreads();
  float se = 0.f;
  for (int n = tid; n < NN; n += 256) se += expf(wl[n] - mx);
  red[tid] = se; __syncthreads();
  for (int s = 128; s > 0; s >>= 1) { if (tid < s) red[tid] += red[tid + s]; __syncthreads(); }
  if (tid == 0) { rowstat[b * 2] = mx; rowstat[b * 2 + 1] = red[0]; }
}

__global__ __launch_bounds__(256) void pooled_kernel(const float* __restrict__ f3,
                                                     const float* __restrict__ wlog,
                                                     const float* __restrict__ rowstat,
                                                     float* __restrict__ pooled) {
  int b = blockIdx.y, chunk = blockIdx.x;
  int tid = threadIdx.x;
  float mx = rowstat[b * 2], inv = 1.0f / rowstat[b * 2 + 1];
  float acc = 0.f;
  int n0 = chunk * 1024;
  for (int n = n0; n < n0 + 1024; ++n) {
    float a = expf(wlog[(size_t)b * NN + n] - mx) * inv;
    acc = fmaf(f3[((size_t)b * NN + n) * 256 + tid], a, acc);
  }
  atomicAdd(&pooled[b * 256 + tid], acc);
}

__global__ __launch_bounds__(256) void final_kernel(const float* __restrict__ pooled,
                                                    const float* __restrict__ Wfc,
                                                    const float* __restrict__ bfc,
                                                    float* __restrict__ out) {
  int b = blockIdx.x, o = threadIdx.x;
  float acc = 0.f;
  for (int c = 0; c < 256; ++c) acc = fmaf(pooled[b * 256 + c], Wfc[c * 256 + o], acc);
  acc += bfc[o];
  out[b * 256 + o] = fmaxf(acc, 0.f);
}

// ---------------------------------------------------------------- launch
static constexpr size_t align256(size_t v) { return (v + 255) & ~(size_t)255; }

extern "C" void kernel_launch(void* const* d_in, const int* in_sizes, int n_in,
                              void* d_out, int out_size, void* d_ws, size_t ws_size,
                              hipStream_t stream) {
  const float* x    = (const float*)d_in[0];
  const float* W1   = (const float*)d_in[1];
  const float* g1   = (const float*)d_in[2];
  const float* b1   = (const float*)d_in[3];
  const float* W2   = (const float*)d_in[4];
  const float* g2   = (const float*)d_in[5];
  const float* b2   = (const float*)d_in[6];
  const float* Ws2a = (const float*)d_in[7];
  const float* bs2a = (const float*)d_in[8];
  const float* Ws2b = (const float*)d_in[9];
  const float* bs2b = (const float*)d_in[10];
  const float* W3   = (const float*)d_in[11];
  const float* g3   = (const float*)d_in[12];
  const float* b3   = (const float*)d_in[13];
  const float* Ws3a = (const float*)d_in[14];
  const float* bs3a = (const float*)d_in[15];
  const float* Ws3b = (const float*)d_in[16];
  const float* bs3b = (const float*)d_in[17];
  const float* Wa1  = (const float*)d_in[18];
  const float* ba1  = (const float*)d_in[19];
  const float* Wa2  = (const float*)d_in[20];
  const float* ba2  = (const float*)d_in[21];
  const float* Wfc  = (const float*)d_in[22];
  const float* bfc  = (const float*)d_in[23];
  float* out = (float*)d_out;

  char* ws = (char*)d_ws;
  size_t off = 0;
  auto take = [&](size_t bytes) { size_t o = off; off = align256(off + bytes); return o; };
  size_t o_nbr  = take((size_t)BB * NN * KP * 4);
  size_t o_f1   = take((size_t)BB * NN * 64 * 4);
  size_t o_f2   = take((size_t)BB * NN * 128 * 4);
  size_t o_f3   = take((size_t)BB * NN * 256 * 4);
  size_t o_U2   = take((size_t)BB * NN * 256 * 4);
  size_t o_UA2  = take((size_t)BB * NN * 128 * 4);
  size_t o_U3   = take((size_t)BB * NN * 512 * 4);
  size_t o_UA3  = take((size_t)BB * NN * 256 * 4);
  size_t o_P2m  = take(64 * 256 * 4);
  size_t o_P2a  = take(64 * 128 * 4);
  size_t o_P3m  = take(128 * 512 * 4);
  size_t o_P3a  = take(128 * 256 * 4);
  size_t o_st   = take(896 * 4);       // stats1(128) stats2(256) stats3(512)
  size_t o_wlog = take((size_t)BB * NN * 4);
  size_t o_rs   = take(16 * 4);
  size_t o_pool = take(BB * 256 * 4);

  int*   nbr   = (int*)(ws + o_nbr);
  float* f1    = (float*)(ws + o_f1);
  float* f2    = (float*)(ws + o_f2);
  float* f3    = (float*)(ws + o_f3);
  float* U2    = (float*)(ws + o_U2);
  float* UA2   = (float*)(ws + o_UA2);
  float* U3    = (float*)(ws + o_U3);
  float* UA3   = (float*)(ws + o_UA3);
  float* P2m   = (float*)(ws + o_P2m);
  float* P2a   = (float*)(ws + o_P2a);
  float* P3m   = (float*)(ws + o_P3m);
  float* P3a   = (float*)(ws + o_P3a);
  float* stats1 = (float*)(ws + o_st);
  float* stats2 = stats1 + 128;
  float* stats3 = stats2 + 256;
  float* wlog  = (float*)(ws + o_wlog);
  float* rowst = (float*)(ws + o_rs);
  float* pooled = (float*)(ws + o_pool);

  hipMemsetAsync(ws + o_st, 0, 896 * 4, stream);
  hipMemsetAsync(ws + o_pool, 0, BB * 256 * 4, stream);

  knn_kernel<<<dim3(NN / 128, BB), 512, 0, stream>>>(x, nbr);
  stats1_kernel<<<dim3(NN / 32, BB), 256, 0, stream>>>(x, nbr, W1, stats1);
  apply1_kernel<<<dim3(NN / 16, BB), 256, 0, stream>>>(x, nbr, W1, g1, b1, stats1, f1);

  pack_kernel<<<(64 * 256 + 255) / 256, 256, 0, stream>>>(W2, P2m, 64, 128);
  pack_kernel<<<(64 * 128 + 255) / 256, 256, 0, stream>>>(Ws2a, P2a, 64, 64);
  pack_kernel<<<(128 * 512 + 255) / 256, 256, 0, stream>>>(W3, P3m, 128, 256);
  pack_kernel<<<(128 * 256 + 255) / 256, 256, 0, stream>>>(Ws3a, P3a, 128, 128);

  gemm128_kernel<64><<<dim3(256 / 128, (BB * NN) / 128), 256, 0, stream>>>(f1, P2m, U2, 256);
  gemm128_kernel<64><<<dim3(128 / 128, (BB * NN) / 128), 256, 0, stream>>>(f1, P2a, UA2, 128);
  soft_stats_kernel<128><<<(BB * NN) / 64, 256, 0, stream>>>(U2, nbr, stats2);
  soft_apply_kernel<128, 64><<<BB * NN, 128, 0, stream>>>(U2, UA2, nbr, stats2, g2, b2,
                                                          bs2a, Ws2b, bs2b, f2);

  gemm128_kernel<128><<<dim3(512 / 128, (BB * NN) / 128), 256, 0, stream>>>(f2, P3m, U3, 512);
  gemm128_kernel<128><<<dim3(256 / 128, (BB * NN) / 128), 256, 0, stream>>>(f2, P3a, UA3, 256);
  soft_stats_kernel<256><<<(BB * NN) / 32, 256, 0, stream>>>(U3, nbr, stats3);
  soft_apply_kernel<256, 128><<<BB * NN, 256, 0, stream>>>(U3, UA3, nbr, stats3, g3, b3,
                                                           bs3a, Ws3b, bs3b, f3);

  wlog_kernel<<<(BB * NN) / 4, 256, 0, stream>>>(f3, Wa1, ba1, Wa2, ba2, wlog);
  poolstat_kernel<<<BB, 256, 0, stream>>>(wlog, rowst);
  pooled_kernel<<<dim3(4, BB), 256, 0, stream>>>(f3, wlog, rowst, pooled);
  final_kernel<<<BB, 256, 0, stream>>>(pooled, Wfc, bfc, out);
}

// Round 9
// 1026.834 us; speedup vs baseline: 1.3680x; 1.1242x over previous
//
#include <hip/hip_runtime.h>
#include <hip/hip_bf16.h>
#include <cstdint>

constexpr int BB = 8;
constexpr int NN = 4096;
constexpr int KN = 10;     // K neighbors used
constexpr int KP = 11;     // K+1 stored
constexpr float EPS_BN = 1e-5f;
constexpr float TAU_V = 0.2f;
constexpr float INV_CNT = 1.0f / (float)(BB * NN * KN);

// ---------------------------------------------------------------- pts4 pack
// pts4[b*N+n] = (x, y, z, x^2+y^2+z^2)  -- same fp expression as before.
__global__ __launch_bounds__(256) void pack_pts_kernel(const float* __restrict__ x,
                                                       float4* __restrict__ pts4) {
  int i = blockIdx.x * 256 + threadIdx.x;
  if (i >= BB * NN) return;
  const float* xp = x + (size_t)i * 5;
  float px = xp[0], py = xp[1], pz = xp[2];
  pts4[i] = make_float4(px, py, pz, px * px + py * py + pz * pz);
}

// ---------------------------------------------------------------- KNN
// One 64-lane wave per query. Lane l owns candidates {t*64+l} (coalesced 1KB
// float4 loads, L2-resident). Branchless top-11 per lane via u64 sortable key
// (sign-fixed dist bits << 32 | idx): dist asc, idx asc on ties == lax.top_k.
// Merge: 11 rounds of wave argmin over list heads via __shfl_xor butterfly.
__global__ __launch_bounds__(256) void knn_kernel(const float4* __restrict__ pts4,
                                                  int* __restrict__ nbr) {
  int lane = threadIdx.x & 63;
  int bn = ((blockIdx.x * 256 + threadIdx.x) >> 6);  // global wave id = query
  int b = bn >> 12;
  const float4* P = pts4 + ((size_t)b << 12);
  float4 q = P[bn & 4095];
  float qx = q.x, qy = q.y, qz = q.z, qs = q.w;
  unsigned long long lst[KP];
#pragma unroll
  for (int j = 0; j < KP; ++j) lst[j] = ~0ull;
  for (int t0 = 0; t0 < 64; t0 += 8) {
    float d[8];
#pragma unroll
    for (int u = 0; u < 8; ++u) {
      float4 p = P[(t0 + u) * 64 + lane];
      // identical contraction as prior passing versions: (qs+sq[m]) - 2*dot
      d[u] = qs + p.w - 2.0f * (qx * p.x + qy * p.y + qz * p.z);
    }
#pragma unroll
    for (int u = 0; u < 8; ++u) {
      unsigned bu = __float_as_uint(d[u]);
      unsigned su = bu ^ (0x80000000u | (unsigned)(((int)bu) >> 31));  // sortable
      unsigned long long key =
          ((unsigned long long)su << 32) | (unsigned)((t0 + u) * 64 + lane);
#pragma unroll
      for (int j = 0; j < KP; ++j) {  // branchless ripple insert
        unsigned long long lo = key < lst[j] ? key : lst[j];
        unsigned long long hi = key < lst[j] ? lst[j] : key;
        lst[j] = lo; key = hi;
      }
    }
  }
  unsigned myw = 0;
#pragma unroll
  for (int t = 0; t < KP; ++t) {
    unsigned long long m = lst[0];
#pragma unroll
    for (int off = 32; off >= 1; off >>= 1) {
      unsigned long long om = __shfl_xor(m, off);
      m = om < m ? om : m;
    }
    bool win = (lst[0] == m);  // keys unique (idx in low bits)
    myw = (lane == t) ? (unsigned)m : myw;
#pragma unroll
    for (int j = 0; j < KP - 1; ++j) lst[j] = win ? lst[j + 1] : lst[j];
    lst[KP - 1] = win ? ~0ull : lst[KP - 1];
  }
  if (lane < KP) nbr[(size_t)bn * KP + lane] = (int)myw;
}

// ---------------------------------------------------------------- layer1 stats
// e1 = [cg-ci(3), ci(3), ag-ai(2), ai(2)] ; y = e1 @ W1 (10x64)
__device__ inline void stage_e1(const float* __restrict__ x, const int* __restrict__ nbr,
                                float (*e1s)[10], int b, int n0, int nedges, int tid, int nthreads) {
  for (int e = tid; e < nedges; e += nthreads) {
    int p = e / KN, k = e - p * KN;
    int n = n0 + p;
    const float* xn = x + ((size_t)b * NN + n) * 5;
    int g = nbr[((size_t)b * NN + n) * KP + k];  // idx1 = first K entries (incl self)
    const float* xg = x + ((size_t)b * NN + g) * 5;
    float cx = xn[0], cy = xn[1], cz = xn[2], a0 = xn[3], a1 = xn[4];
    e1s[e][0] = xg[0] - cx; e1s[e][1] = xg[1] - cy; e1s[e][2] = xg[2] - cz;
    e1s[e][3] = cx;         e1s[e][4] = cy;         e1s[e][5] = cz;
    e1s[e][6] = xg[3] - a0; e1s[e][7] = xg[4] - a1;
    e1s[e][8] = a0;         e1s[e][9] = a1;
  }
}

__global__ __launch_bounds__(256) void stats1_kernel(const float* __restrict__ x,
                                                     const int* __restrict__ nbr,
                                                     const float* __restrict__ W1,
                                                     float* __restrict__ stats) {
  constexpr int PPB = 32;
  __shared__ float e1s[PPB * KN][10];
  __shared__ float W1s[10][64];
  __shared__ float red[256];
  int b = blockIdx.y;
  int n0 = blockIdx.x * PPB;
  int tid = threadIdx.x;
  for (int i = tid; i < 640; i += 256) W1s[i / 64][i % 64] = W1[i];
  stage_e1(x, nbr, e1s, b, n0, PPB * KN, tid, 256);
  __syncthreads();
  int c = tid & 63, lane = tid >> 6;
  float s = 0.f, ss = 0.f;
  for (int e = lane; e < PPB * KN; e += 4) {
    float y = 0.f;
#pragma unroll
    for (int i = 0; i < 10; ++i) y = fmaf(e1s[e][i], W1s[i][c], y);
    s += y; ss += y * y;
  }
  red[tid] = s; __syncthreads();
  float s4 = 0.f, ss4 = 0.f;
  if (lane == 0) s4 = red[c] + red[c + 64] + red[c + 128] + red[c + 192];
  __syncthreads();
  red[tid] = ss; __syncthreads();
  if (lane == 0) {
    ss4 = red[c] + red[c + 64] + red[c + 128] + red[c + 192];
    atomicAdd(&stats[c], s4);
    atomicAdd(&stats[64 + c], ss4);
  }
}

__global__ __launch_bounds__(256) void apply1_kernel(const float* __restrict__ x,
                                                     const int* __restrict__ nbr,
                                                     const float* __restrict__ W1,
                                                     const float* __restrict__ g1,
                                                     const float* __restrict__ b1,
                                                     const float* __restrict__ stats,
                                                     float* __restrict__ f1) {
  constexpr int PPB = 16;
  __shared__ float e1s[PPB * KN][10];
  __shared__ float W1s[10][64];
  int b = blockIdx.y;
  int n0 = blockIdx.x * PPB;
  int tid = threadIdx.x;
  for (int i = tid; i < 640; i += 256) W1s[i / 64][i % 64] = W1[i];
  stage_e1(x, nbr, e1s, b, n0, PPB * KN, tid, 256);
  __syncthreads();
  int c = tid & 63, pl = tid >> 6;
  float mean = stats[c] * INV_CNT;
  float var = stats[64 + c] * INV_CNT - mean * mean;
  float scale = g1[c] * rsqrtf(var + EPS_BN);
  float shift = b1[c] - mean * scale;
  for (int p = pl; p < PPB; p += 4) {
    float mx = 0.0f;  // relu outputs are >= 0
#pragma unroll
    for (int k = 0; k < KN; ++k) {
      float y = 0.f;
#pragma unroll
      for (int i = 0; i < 10; ++i) y = fmaf(e1s[p * KN + k][i], W1s[i][c], y);
      float h = scale * y + shift;
      mx = fmaxf(mx, h);
    }
    f1[((size_t)b * NN + n0 + p) * 64 + c] = mx;
  }
}

// ---------------------------------------------------------------- weight packing
__global__ void pack_kernel(const float* __restrict__ src, float* __restrict__ dst,
                            int Kh, int Nout) {
  int idx = blockIdx.x * 256 + threadIdx.x;
  int tot = Kh * 2 * Nout;
  if (idx >= tot) return;
  int k = idx / (2 * Nout);
  int j = idx - k * 2 * Nout;
  float v;
  if (j < Nout) v = src[k * Nout + j];
  else { int jj = j - Nout; v = src[(Kh + k) * Nout + jj] - src[k * Nout + jj]; }
  dst[idx] = v;
}

// ---------------------------------------------------------------- tiled SGEMM
// 128x128 tile, 256 threads, 8x8 acc in 2x2 split sub-tiles.
template <int Kd>
__global__ __launch_bounds__(256) void gemm128_kernel(const float* __restrict__ A,
                                                      const float* __restrict__ P,
                                                      float* __restrict__ C, int Nc) {
  __shared__ float As[16][132];
  __shared__ float Bs[16][128];
  int tid = threadIdx.x;
  int tx = tid & 15, ty = tid >> 4;
  int r0 = blockIdx.y * 128, c0 = blockIdx.x * 128;
  float acc[8][8] = {};
  for (int k0 = 0; k0 < Kd; k0 += 16) {
    for (int e = tid; e < 512; e += 256) {
      int r = e >> 2, kq = (e & 3) * 4;
      float4 v = *(const float4*)&A[(size_t)(r0 + r) * Kd + k0 + kq];
      As[kq + 0][r] = v.x; As[kq + 1][r] = v.y; As[kq + 2][r] = v.z; As[kq + 3][r] = v.w;
    }
    for (int e = tid; e < 512; e += 256) {
      int kk = e >> 5, cc = (e & 31) * 4;
      *(float4*)&Bs[kk][cc] = *(const float4*)&P[(size_t)(k0 + kk) * Nc + c0 + cc];
    }
    __syncthreads();
#pragma unroll
    for (int kk = 0; kk < 16; ++kk) {
      float4 a0 = *(const float4*)&As[kk][ty * 4];
      float4 a1 = *(const float4*)&As[kk][64 + ty * 4];
      float4 b0 = *(const float4*)&Bs[kk][tx * 4];
      float4 b1 = *(const float4*)&Bs[kk][64 + tx * 4];
      float a[8] = {a0.x, a0.y, a0.z, a0.w, a1.x, a1.y, a1.z, a1.w};
      float bb[8] = {b0.x, b0.y, b0.z, b0.w, b1.x, b1.y, b1.z, b1.w};
#pragma unroll
      for (int i = 0; i < 8; ++i)
#pragma unroll
        for (int j = 0; j < 8; ++j) acc[i][j] = fmaf(a[i], bb[j], acc[i][j]);
    }
    __syncthreads();
  }
#pragma unroll
  for (int i = 0; i < 8; ++i) {
    int r = r0 + ((i < 4) ? (ty * 4 + i) : (64 + ty * 4 + i - 4));
    float4 lo = make_float4(acc[i][0], acc[i][1], acc[i][2], acc[i][3]);
    float4 hi = make_float4(acc[i][4], acc[i][5], acc[i][6], acc[i][7]);
    *(float4*)&C[(size_t)r * Nc + c0 + tx * 4] = lo;
    *(float4*)&C[(size_t)r * Nc + c0 + 64 + tx * 4] = hi;
  }
}

// ---------------------------------------------------------------- soft-edge stats
// Wave-per-point: lane covers C/64 channels (float4/float2); 11 independent
// coalesced row loads per point; register accum -> LDS block reduce -> 1
// atomicAdd per channel per block.
template <int C>
__global__ __launch_bounds__(256) void soft_stats_kernel(const float* __restrict__ U,
                                                         const int* __restrict__ nbr,
                                                         float* __restrict__ stats) {
  constexpr int VEC = C / 64;  // 4 (C=256) or 2 (C=128)
  int tid = threadIdx.x;
  int lane = tid & 63;
  int wid = tid >> 6;
  int gw = blockIdx.x * 4 + wid;
  int nw = gridDim.x * 4;
  float s[VEC] = {}, ss[VEC] = {};
  for (int bn = gw; bn < BB * NN; bn += nw) {
    int b = bn >> 12;
    const int* ix = nbr + (size_t)bn * KP;
    const float* Ub = U + ((size_t)(b << 12)) * (2 * C);
    float dv[VEC];
    if constexpr (VEC == 4) {
      float4 t = *(const float4*)(U + (size_t)bn * (2 * C) + C + lane * 4);
      dv[0] = t.x; dv[1] = t.y; dv[2] = t.z; dv[3] = t.w;
    } else {
      float2 t = *(const float2*)(U + (size_t)bn * (2 * C) + C + lane * 2);
      dv[0] = t.x; dv[1] = t.y;
    }
    int rows[KN];
#pragma unroll
    for (int k = 0; k < KN; ++k) rows[k] = ix[k + 1];
#pragma unroll
    for (int k = 0; k < KN; ++k) {
      float uv[VEC];
      if constexpr (VEC == 4) {
        float4 t = *(const float4*)(Ub + (size_t)rows[k] * (2 * C) + lane * 4);
        uv[0] = t.x; uv[1] = t.y; uv[2] = t.z; uv[3] = t.w;
      } else {
        float2 t = *(const float2*)(Ub + (size_t)rows[k] * (2 * C) + lane * 2);
        uv[0] = t.x; uv[1] = t.y;
      }
#pragma unroll
      for (int v = 0; v < VEC; ++v) {
        float y = uv[v] + dv[v];
        s[v] += y; ss[v] += y * y;
      }
    }
  }
  __shared__ float reds[4][C];
  __shared__ float redss[4][C];
#pragma unroll
  for (int v = 0; v < VEC; ++v) {
    reds[wid][lane * VEC + v] = s[v];
    redss[wid][lane * VEC + v] = ss[v];
  }
  __syncthreads();
  if (tid < C) {
    float a = reds[0][tid] + reds[1][tid] + reds[2][tid] + reds[3][tid];
    float a2 = redss[0][tid] + redss[1][tid] + redss[2][tid] + redss[3][tid];
    atomicAdd(&stats[tid], a);
    atomicAdd(&stats[C + tid], a2);
  }
}

// ---------------------------------------------------------------- soft-edge apply
template <int C, int CA>
__global__ __launch_bounds__(C) void soft_apply_kernel(const float* __restrict__ U,
                                                       const float* __restrict__ UA,
                                                       const int* __restrict__ nbr,
                                                       const float* __restrict__ stats,
                                                       const float* __restrict__ gbn,
                                                       const float* __restrict__ bbn,
                                                       const float* __restrict__ ba,
                                                       const float* __restrict__ Wb,
                                                       const float* __restrict__ bbv,
                                                       float* __restrict__ fout) {
  __shared__ int ixs[KN];
  __shared__ float logits[KN];
  __shared__ float parts[KN][2];
  int tid = threadIdx.x;
  int bn = blockIdx.x;
  int b = bn >> 12;
  if (tid < KN) ixs[tid] = nbr[(size_t)bn * KP + 1 + tid];
  __syncthreads();
  float pv[KN];
  if (tid < CA) {
    float da = UA[(size_t)bn * (2 * CA) + CA + tid] + ba[tid];
    float wbj = Wb[tid];
#pragma unroll
    for (int k = 0; k < KN; ++k) {
      int row = ixs[k];
      float h = UA[((size_t)(b << 12) + row) * (2 * CA) + tid] + da;
      h = fmaxf(h, 0.f);
      pv[k] = h * wbj;
    }
  } else {
#pragma unroll
    for (int k = 0; k < KN; ++k) pv[k] = 0.f;
  }
#pragma unroll
  for (int k = 0; k < KN; ++k) {
    float v = pv[k];
    for (int off = 32; off >= 1; off >>= 1) v += __shfl_down(v, off);
    if ((tid & 63) == 0 && tid < CA) parts[k][tid >> 6] = v;
  }
  __syncthreads();
  if (tid == 0) {
    float bsv = bbv[0];
#pragma unroll
    for (int k = 0; k < KN; ++k) {
      float l = parts[k][0];
      if (CA == 128) l += parts[k][1];
      logits[k] = (l + bsv) * (1.0f / TAU_V);
    }
  }
  __syncthreads();
  float lg[KN], mx = -3.4e38f;
#pragma unroll
  for (int k = 0; k < KN; ++k) { lg[k] = logits[k]; mx = fmaxf(mx, lg[k]); }
  float se = 0.f;
#pragma unroll
  for (int k = 0; k < KN; ++k) { lg[k] = expf(lg[k] - mx); se += lg[k]; }
  float inv = 1.0f / se;
  int c = tid;
  float mean = stats[c] * INV_CNT;
  float var = stats[C + c] * INV_CNT - mean * mean;
  float scale = gbn[c] * rsqrtf(var + EPS_BN);
  float shift = bbn[c] - mean * scale;
  float d = U[(size_t)bn * (2 * C) + C + c];
  float acc = 0.f;
#pragma unroll
  for (int k = 0; k < KN; ++k) {
    int row = ixs[k];
    float y = U[((size_t)(b << 12) + row) * (2 * C) + c] + d;
    float h = fmaxf(scale * y + shift, 0.f);
    acc += h * lg[k];
  }
  fout[(size_t)bn * C + c] = acc * inv;
}

// ---------------------------------------------------------------- global attention pool
__global__ __launch_bounds__(256) void wlog_kernel(const float* __restrict__ f3,
                                                   const float* __restrict__ Wa1,
                                                   const float* __restrict__ ba1,
                                                   const float* __restrict__ Wa2,
                                                   const float* __restrict__ ba2,
                                                   float* __restrict__ wlog) {
  int tid = threadIdx.x;
  int j = tid & 63, w = tid >> 6;
  int bn = blockIdx.x * 4 + w;
  const float* f = f3 + (size_t)bn * 256;
  float acc = 0.f;
  for (int cidx = 0; cidx < 256; ++cidx) acc = fmaf(f[cidx], Wa1[cidx * 64 + j], acc);
  acc += ba1[j];
  acc = fmaxf(acc, 0.f);
  float v = acc * Wa2[j];
  for (int off = 32; off >= 1; off >>= 1) v += __shfl_down(v, off);
  if (j == 0) wlog[bn] = v + ba2[0];
}

__global__ __launch_bounds__(256) void poolstat_kernel(const float* __restrict__ wlog,
                                                       float* __restrict__ rowstat) {
  __shared__ float red[256];
  int b = blockIdx.x, tid = threadIdx.x;
  const float* wl = wlog + (size_t)b * NN;
  float mx = -3.4e38f;
  for (int n = tid; n < NN; n += 256) mx = fmaxf(mx, wl[n]);
  red[tid] = mx; __syncthreads();
  for (int s = 128; s > 0; s >>= 1) { if (tid < s) red[tid] = fmaxf(red[tid], red[tid + s]); __syncthreads(); }
  mx = red[0]; __syncthreads();
  float se = 0.f;
  for (int n = tid; n < NN; n += 256) se += expf(wl[n] - mx);
  red[tid] = se; __syncthreads();
  for (int s = 128; s > 0; s >>= 1) { if (tid < s) red[tid] += red[tid + s]; __syncthreads(); }
  if (tid == 0) { rowstat[b * 2] = mx; rowstat[b * 2 + 1] = red[0]; }
}

__global__ __launch_bounds__(256) void pooled_kernel(const float* __restrict__ f3,
                                                     const float* __restrict__ wlog,
                                                     const float* __restrict__ rowstat,
                                                     float* __restrict__ pooled) {
  int b = blockIdx.y, chunk = blockIdx.x;
  int tid = threadIdx.x;
  float mx = rowstat[b * 2], inv = 1.0f / rowstat[b * 2 + 1];
  float acc = 0.f;
  int n0 = chunk * 1024;
  for (int n = n0; n < n0 + 1024; ++n) {
    float a = expf(wlog[(size_t)b * NN + n] - mx) * inv;
    acc = fmaf(f3[((size_t)b * NN + n) * 256 + tid], a, acc);
  }
  atomicAdd(&pooled[b * 256 + tid], acc);
}

__global__ __launch_bounds__(256) void final_kernel(const float* __restrict__ pooled,
                                                    const float* __restrict__ Wfc,
                                                    const float* __restrict__ bfc,
                                                    float* __restrict__ out) {
  int b = blockIdx.x, o = threadIdx.x;
  float acc = 0.f;
  for (int c = 0; c < 256; ++c) acc = fmaf(pooled[b * 256 + c], Wfc[c * 256 + o], acc);
  acc += bfc[o];
  out[b * 256 + o] = fmaxf(acc, 0.f);
}

// ---------------------------------------------------------------- launch
static constexpr size_t align256(size_t v) { return (v + 255) & ~(size_t)255; }

extern "C" void kernel_launch(void* const* d_in, const int* in_sizes, int n_in,
                              void* d_out, int out_size, void* d_ws, size_t ws_size,
                              hipStream_t stream) {
  const float* x    = (const float*)d_in[0];
  const float* W1   = (const float*)d_in[1];
  const float* g1   = (const float*)d_in[2];
  const float* b1   = (const float*)d_in[3];
  const float* W2   = (const float*)d_in[4];
  const float* g2   = (const float*)d_in[5];
  const float* b2   = (const float*)d_in[6];
  const float* Ws2a = (const float*)d_in[7];
  const float* bs2a = (const float*)d_in[8];
  const float* Ws2b = (const float*)d_in[9];
  const float* bs2b = (const float*)d_in[10];
  const float* W3   = (const float*)d_in[11];
  const float* g3   = (const float*)d_in[12];
  const float* b3   = (const float*)d_in[13];
  const float* Ws3a = (const float*)d_in[14];
  const float* bs3a = (const float*)d_in[15];
  const float* Ws3b = (const float*)d_in[16];
  const float* bs3b = (const float*)d_in[17];
  const float* Wa1  = (const float*)d_in[18];
  const float* ba1  = (const float*)d_in[19];
  const float* Wa2  = (const float*)d_in[20];
  const float* ba2  = (const float*)d_in[21];
  const float* Wfc  = (const float*)d_in[22];
  const float* bfc  = (const float*)d_in[23];
  float* out = (float*)d_out;

  char* ws = (char*)d_ws;
  size_t off = 0;
  auto take = [&](size_t bytes) { size_t o = off; off = align256(off + bytes); return o; };
  size_t o_nbr  = take((size_t)BB * NN * KP * 4);
  size_t o_p4   = take((size_t)BB * NN * 16);
  size_t o_f1   = take((size_t)BB * NN * 64 * 4);
  size_t o_f2   = take((size_t)BB * NN * 128 * 4);
  size_t o_f3   = take((size_t)BB * NN * 256 * 4);
  size_t o_U2   = take((size_t)BB * NN * 256 * 4);
  size_t o_UA2  = take((size_t)BB * NN * 128 * 4);
  size_t o_U3   = take((size_t)BB * NN * 512 * 4);
  size_t o_UA3  = take((size_t)BB * NN * 256 * 4);
  size_t o_P2m  = take(64 * 256 * 4);
  size_t o_P2a  = take(64 * 128 * 4);
  size_t o_P3m  = take(128 * 512 * 4);
  size_t o_P3a  = take(128 * 256 * 4);
  size_t o_st   = take(896 * 4);       // stats1(128) stats2(256) stats3(512)
  size_t o_wlog = take((size_t)BB * NN * 4);
  size_t o_rs   = take(16 * 4);
  size_t o_pool = take(BB * 256 * 4);

  int*    nbr   = (int*)(ws + o_nbr);
  float4* pts4  = (float4*)(ws + o_p4);
  float*  f1    = (float*)(ws + o_f1);
  float*  f2    = (float*)(ws + o_f2);
  float*  f3    = (float*)(ws + o_f3);
  float*  U2    = (float*)(ws + o_U2);
  float*  UA2   = (float*)(ws + o_UA2);
  float*  U3    = (float*)(ws + o_U3);
  float*  UA3   = (float*)(ws + o_UA3);
  float*  P2m   = (float*)(ws + o_P2m);
  float*  P2a   = (float*)(ws + o_P2a);
  float*  P3m   = (float*)(ws + o_P3m);
  float*  P3a   = (float*)(ws + o_P3a);
  float*  stats1 = (float*)(ws + o_st);
  float*  stats2 = stats1 + 128;
  float*  stats3 = stats2 + 256;
  float*  wlog  = (float*)(ws + o_wlog);
  float*  rowst = (float*)(ws + o_rs);
  float*  pooled = (float*)(ws + o_pool);

  hipMemsetAsync(ws + o_st, 0, 896 * 4, stream);
  hipMemsetAsync(ws + o_pool, 0, BB * 256 * 4, stream);

  pack_pts_kernel<<<(BB * NN + 255) / 256, 256, 0, stream>>>(x, pts4);
  knn_kernel<<<(BB * NN) / 4, 256, 0, stream>>>(pts4, nbr);
  stats1_kernel<<<dim3(NN / 32, BB), 256, 0, stream>>>(x, nbr, W1, stats1);
  apply1_kernel<<<dim3(NN / 16, BB), 256, 0, stream>>>(x, nbr, W1, g1, b1, stats1, f1);

  pack_kernel<<<(64 * 256 + 255) / 256, 256, 0, stream>>>(W2, P2m, 64, 128);
  pack_kernel<<<(64 * 128 + 255) / 256, 256, 0, stream>>>(Ws2a, P2a, 64, 64);
  pack_kernel<<<(128 * 512 + 255) / 256, 256, 0, stream>>>(W3, P3m, 128, 256);
  pack_kernel<<<(128 * 256 + 255) / 256, 256, 0, stream>>>(Ws3a, P3a, 128, 128);

  gemm128_kernel<64><<<dim3(256 / 128, (BB * NN) / 128), 256, 0, stream>>>(f1, P2m, U2, 256);
  gemm128_kernel<64><<<dim3(128 / 128, (BB * NN) / 128), 256, 0, stream>>>(f1, P2a, UA2, 128);
  soft_stats_kernel<128><<<512, 256, 0, stream>>>(U2, nbr, stats2);
  soft_apply_kernel<128, 64><<<BB * NN, 128, 0, stream>>>(U2, UA2, nbr, stats2, g2, b2,
                                                          bs2a, Ws2b, bs2b, f2);

  gemm128_kernel<128><<<dim3(512 / 128, (BB * NN) / 128), 256, 0, stream>>>(f2, P3m, U3, 512);
  gemm128_kernel<128><<<dim3(256 / 128, (BB * NN) / 128), 256, 0, stream>>>(f2, P3a, UA3, 256);
  soft_stats_kernel<256><<<512, 256, 0, stream>>>(U3, nbr, stats3);
  soft_apply_kernel<256, 128><<<BB * NN, 256, 0, stream>>>(U3, UA3, nbr, stats3, g3, b3,
                                                           bs3a, Ws3b, bs3b, f3);

  wlog_kernel<<<(BB * NN) / 4, 256, 0, stream>>>(f3, Wa1, ba1, Wa2, ba2, wlog);
  poolstat_kernel<<<BB, 256, 0, stream>>>(wlog, rowst);
  pooled_kernel<<<dim3(4, BB), 256, 0, stream>>>(f3, wlog, rowst, pooled);
  final_kernel<<<BB, 256, 0, stream>>>(pooled, Wfc, bfc, out);
}

// Round 13
// 791.660 us; speedup vs baseline: 1.7744x; 1.2971x over previous
//
#include <hip/hip_runtime.h>
#include <hip/hip_bf16.h>
#include <cstdint>

constexpr int BB = 8;
constexpr int NN = 4096;
constexpr int KN = 10;     // K neighbors used
constexpr int KP = 11;     // K+1 stored
constexpr float EPS_BN = 1e-5f;
constexpr float TAU_V = 0.2f;
constexpr float INV_CNT = 1.0f / (float)(BB * NN * KN);

// ---------------------------------------------------------------- pts4 pack
__global__ __launch_bounds__(256) void pack_pts_kernel(const float* __restrict__ x,
                                                       float4* __restrict__ pts4) {
  int i = blockIdx.x * 256 + threadIdx.x;
  if (i >= BB * NN) return;
  const float* xp = x + (size_t)i * 5;
  float px = xp[0], py = xp[1], pz = xp[2];
  pts4[i] = make_float4(px, py, pz, px * px + py * py + pz * pz);
}

// ---------------------------------------------------------------- KNN
// Wave per query. Pass A: per-lane min over its 64 candidates; bitonic
// shfl-sort of the 64 lane-minima gives T = 11th smallest lane-min, a proven
// upper bound on the global 11th distance (11 lanes with min <= T each hold a
// distinct candidate <= T). Pass B: recompute d; only iterations where
// __any(d <= Tg) run the branchless u64 ripple (survivors ~20/4096 -> ~30% of
// iterations). Keys (sign-fixed dist << 32 | idx) keep lax.top_k tie order.
__global__ __launch_bounds__(256) void knn_kernel(const float4* __restrict__ pts4,
                                                  int* __restrict__ nbr) {
  int lane = threadIdx.x & 63;
  int bn = ((blockIdx.x * 256 + threadIdx.x) >> 6);  // global wave id = query
  int b = bn >> 12;
  const float4* P = pts4 + ((size_t)b << 12);
  float4 q = P[bn & 4095];
  float qx = q.x, qy = q.y, qz = q.z, qs = q.w;
  // ---- Pass A: lane min
  float mn = 3.4e38f;
  for (int t0 = 0; t0 < 64; t0 += 8) {
    float d[8];
#pragma unroll
    for (int u = 0; u < 8; ++u) {
      float4 p = P[(t0 + u) * 64 + lane];
      d[u] = qs + p.w - 2.0f * (qx * p.x + qy * p.y + qz * p.z);
    }
#pragma unroll
    for (int u = 0; u < 8; ++u) mn = fminf(mn, d[u]);
  }
  // ---- bitonic sort of minima across 64 lanes (ascending), T = value at lane 10
  float v = mn;
#pragma unroll
  for (int k = 2; k <= 64; k <<= 1) {
#pragma unroll
    for (int j = k >> 1; j >= 1; j >>= 1) {
      float o = __shfl_xor(v, j);
      bool keepmin = (((lane & j) == 0) == ((lane & k) == 0));
      v = keepmin ? fminf(v, o) : fmaxf(v, o);
    }
  }
  float T = __shfl(v, 10);
  float Tg = T + fabsf(T) * 2e-7f + 1e-35f;  // ulp slack vs cross-loop codegen
  // ---- Pass B: gated ripple
  unsigned long long lst[KP];
#pragma unroll
  for (int j = 0; j < KP; ++j) lst[j] = ~0ull;
  for (int t0 = 0; t0 < 64; t0 += 8) {
    float d[8];
#pragma unroll
    for (int u = 0; u < 8; ++u) {
      float4 p = P[(t0 + u) * 64 + lane];
      d[u] = qs + p.w - 2.0f * (qx * p.x + qy * p.y + qz * p.z);
    }
#pragma unroll
    for (int u = 0; u < 8; ++u) {
      if (__any(d[u] <= Tg)) {
        float dv = d[u];
        unsigned bu = __float_as_uint(dv);
        unsigned su = bu ^ (0x80000000u | (unsigned)(((int)bu) >> 31));
        unsigned long long key =
            ((unsigned long long)su << 32) | (unsigned)((t0 + u) * 64 + lane);
        if (!(dv <= Tg)) key = ~0ull;  // non-qualifying lanes: no-op insert
#pragma unroll
        for (int j = 0; j < KP; ++j) {
          unsigned long long lo = key < lst[j] ? key : lst[j];
          unsigned long long hi = key < lst[j] ? lst[j] : key;
          lst[j] = lo; key = hi;
        }
      }
    }
  }
  // ---- merge: 11 rounds of wave argmin-pop
  unsigned myw = 0;
#pragma unroll
  for (int t = 0; t < KP; ++t) {
    unsigned long long m = lst[0];
#pragma unroll
    for (int off = 32; off >= 1; off >>= 1) {
      unsigned long long om = __shfl_xor(m, off);
      m = om < m ? om : m;
    }
    bool win = (lst[0] == m);  // keys unique (idx in low bits)
    myw = (lane == t) ? (unsigned)m : myw;
#pragma unroll
    for (int j = 0; j < KP - 1; ++j) lst[j] = win ? lst[j + 1] : lst[j];
    lst[KP - 1] = win ? ~0ull : lst[KP - 1];
  }
  if (lane < KP) nbr[(size_t)bn * KP + lane] = (int)myw;
}

// ---------------------------------------------------------------- layer1 stats
// e1 = [cg-ci(3), ci(3), ag-ai(2), ai(2)] ; y = e1 @ W1 (10x64)
__device__ inline void stage_e1(const float* __restrict__ x, const int* __restrict__ nbr,
                                float (*e1s)[10], int b, int n0, int nedges, int tid, int nthreads) {
  for (int e = tid; e < nedges; e += nthreads) {
    int p = e / KN, k = e - p * KN;
    int n = n0 + p;
    const float* xn = x + ((size_t)b * NN + n) * 5;
    int g = nbr[((size_t)b * NN + n) * KP + k];  // idx1 = first K entries (incl self)
    const float* xg = x + ((size_t)b * NN + g) * 5;
    float cx = xn[0], cy = xn[1], cz = xn[2], a0 = xn[3], a1 = xn[4];
    e1s[e][0] = xg[0] - cx; e1s[e][1] = xg[1] - cy; e1s[e][2] = xg[2] - cz;
    e1s[e][3] = cx;         e1s[e][4] = cy;         e1s[e][5] = cz;
    e1s[e][6] = xg[3] - a0; e1s[e][7] = xg[4] - a1;
    e1s[e][8] = a0;         e1s[e][9] = a1;
  }
}

__global__ __launch_bounds__(256) void stats1_kernel(const float* __restrict__ x,
                                                     const int* __restrict__ nbr,
                                                     const float* __restrict__ W1,
                                                     float* __restrict__ stats) {
  constexpr int PPB = 32;
  __shared__ float e1s[PPB * KN][10];
  __shared__ float W1s[10][64];
  __shared__ float red[256];
  int b = blockIdx.y;
  int n0 = blockIdx.x * PPB;
  int tid = threadIdx.x;
  for (int i = tid; i < 640; i += 256) W1s[i / 64][i % 64] = W1[i];
  stage_e1(x, nbr, e1s, b, n0, PPB * KN, tid, 256);
  __syncthreads();
  int c = tid & 63, lane = tid >> 6;
  float s = 0.f, ss = 0.f;
  for (int e = lane; e < PPB * KN; e += 4) {
    float y = 0.f;
#pragma unroll
    for (int i = 0; i < 10; ++i) y = fmaf(e1s[e][i], W1s[i][c], y);
    s += y; ss += y * y;
  }
  red[tid] = s; __syncthreads();
  float s4 = 0.f, ss4 = 0.f;
  if (lane == 0) s4 = red[c] + red[c + 64] + red[c + 128] + red[c + 192];
  __syncthreads();
  red[tid] = ss; __syncthreads();
  if (lane == 0) {
    ss4 = red[c] + red[c + 64] + red[c + 128] + red[c + 192];
    atomicAdd(&stats[c], s4);
    atomicAdd(&stats[64 + c], ss4);
  }
}

__global__ __launch_bounds__(256) void apply1_kernel(const float* __restrict__ x,
                                                     const int* __restrict__ nbr,
                                                     const float* __restrict__ W1,
                                                     const float* __restrict__ g1,
                                                     const float* __restrict__ b1,
                                                     const float* __restrict__ stats,
                                                     float* __restrict__ f1) {
  constexpr int PPB = 16;
  __shared__ float e1s[PPB * KN][10];
  __shared__ float W1s[10][64];
  int b = blockIdx.y;
  int n0 = blockIdx.x * PPB;
  int tid = threadIdx.x;
  for (int i = tid; i < 640; i += 256) W1s[i / 64][i % 64] = W1[i];
  stage_e1(x, nbr, e1s, b, n0, PPB * KN, tid, 256);
  __syncthreads();
  int c = tid & 63, pl = tid >> 6;
  float mean = stats[c] * INV_CNT;
  float var = stats[64 + c] * INV_CNT - mean * mean;
  float scale = g1[c] * rsqrtf(var + EPS_BN);
  float shift = b1[c] - mean * scale;
  for (int p = pl; p < PPB; p += 4) {
    float mx = 0.0f;  // relu outputs are >= 0
#pragma unroll
    for (int k = 0; k < KN; ++k) {
      float y = 0.f;
#pragma unroll
      for (int i = 0; i < 10; ++i) y = fmaf(e1s[p * KN + k][i], W1s[i][c], y);
      float h = scale * y + shift;
      mx = fmaxf(mx, h);
    }
    f1[((size_t)b * NN + n0 + p) * 64 + c] = mx;
  }
}

// ---------------------------------------------------------------- weight packing
__global__ void pack_kernel(const float* __restrict__ src, float* __restrict__ dst,
                            int Kh, int Nout) {
  int idx = blockIdx.x * 256 + threadIdx.x;
  int tot = Kh * 2 * Nout;
  if (idx >= tot) return;
  int k = idx / (2 * Nout);
  int j = idx - k * 2 * Nout;
  float v;
  if (j < Nout) v = src[k * Nout + j];
  else { int jj = j - Nout; v = src[(Kh + k) * Nout + jj] - src[k * Nout + jj]; }
  dst[idx] = v;
}

// ---------------------------------------------------------------- tiled SGEMM
// 128x128 tile, 256 threads, 8x8 acc in 2x2 split sub-tiles.
template <int Kd>
__global__ __launch_bounds__(256) void gemm128_kernel(const float* __restrict__ A,
                                                      const float* __restrict__ P,
                                                      float* __restrict__ C, int Nc) {
  __shared__ float As[16][132];
  __shared__ float Bs[16][128];
  int tid = threadIdx.x;
  int tx = tid & 15, ty = tid >> 4;
  int r0 = blockIdx.y * 128, c0 = blockIdx.x * 128;
  float acc[8][8] = {};
  for (int k0 = 0; k0 < Kd; k0 += 16) {
    for (int e = tid; e < 512; e += 256) {
      int r = e >> 2, kq = (e & 3) * 4;
      float4 v = *(const float4*)&A[(size_t)(r0 + r) * Kd + k0 + kq];
      As[kq + 0][r] = v.x; As[kq + 1][r] = v.y; As[kq + 2][r] = v.z; As[kq + 3][r] = v.w;
    }
    for (int e = tid; e < 512; e += 256) {
      int kk = e >> 5, cc = (e & 31) * 4;
      *(float4*)&Bs[kk][cc] = *(const float4*)&P[(size_t)(k0 + kk) * Nc + c0 + cc];
    }
    __syncthreads();
#pragma unroll
    for (int kk = 0; kk < 16; ++kk) {
      float4 a0 = *(const float4*)&As[kk][ty * 4];
      float4 a1 = *(const float4*)&As[kk][64 + ty * 4];
      float4 b0 = *(const float4*)&Bs[kk][tx * 4];
      float4 b1 = *(const float4*)&Bs[kk][64 + tx * 4];
      float a[8] = {a0.x, a0.y, a0.z, a0.w, a1.x, a1.y, a1.z, a1.w};
      float bb[8] = {b0.x, b0.y, b0.z, b0.w, b1.x, b1.y, b1.z, b1.w};
#pragma unroll
      for (int i = 0; i < 8; ++i)
#pragma unroll
        for (int j = 0; j < 8; ++j) acc[i][j] = fmaf(a[i], bb[j], acc[i][j]);
    }
    __syncthreads();
  }
#pragma unroll
  for (int i = 0; i < 8; ++i) {
    int r = r0 + ((i < 4) ? (ty * 4 + i) : (64 + ty * 4 + i - 4));
    float4 lo = make_float4(acc[i][0], acc[i][1], acc[i][2], acc[i][3]);
    float4 hi = make_float4(acc[i][4], acc[i][5], acc[i][6], acc[i][7]);
    *(float4*)&C[(size_t)r * Nc + c0 + tx * 4] = lo;
    *(float4*)&C[(size_t)r * Nc + c0 + 64 + tx * 4] = hi;
  }
}

// ---------------------------------------------------------------- soft-edge stats
// Wave-per-point: lane covers C/64 channels; vector gathers; register accum ->
// LDS block reduce -> 1 atomicAdd per channel per block.
template <int C>
__global__ __launch_bounds__(256) void soft_stats_kernel(const float* __restrict__ U,
                                                         const int* __restrict__ nbr,
                                                         float* __restrict__ stats) {
  constexpr int VEC = C / 64;  // 4 (C=256) or 2 (C=128)
  int tid = threadIdx.x;
  int lane = tid & 63;
  int wid = tid >> 6;
  int gw = blockIdx.x * 4 + wid;
  int nw = gridDim.x * 4;
  float s[VEC] = {}, ss[VEC] = {};
  for (int bn = gw; bn < BB * NN; bn += nw) {
    int b = bn >> 12;
    const int* ix = nbr + (size_t)bn * KP;
    const float* Ub = U + ((size_t)(b << 12)) * (2 * C);
    float dv[VEC];
    if constexpr (VEC == 4) {
      float4 t = *(const float4*)(U + (size_t)bn * (2 * C) + C + lane * 4);
      dv[0] = t.x; dv[1] = t.y; dv[2] = t.z; dv[3] = t.w;
    } else {
      float2 t = *(const float2*)(U + (size_t)bn * (2 * C) + C + lane * 2);
      dv[0] = t.x; dv[1] = t.y;
    }
    int rows[KN];
#pragma unroll
    for (int k = 0; k < KN; ++k) rows[k] = ix[k + 1];
#pragma unroll
    for (int k = 0; k < KN; ++k) {
      float uv[VEC];
      if constexpr (VEC == 4) {
        float4 t = *(const float4*)(Ub + (size_t)rows[k] * (2 * C) + lane * 4);
        uv[0] = t.x; uv[1] = t.y; uv[2] = t.z; uv[3] = t.w;
      } else {
        float2 t = *(const float2*)(Ub + (size_t)rows[k] * (2 * C) + lane * 2);
        uv[0] = t.x; uv[1] = t.y;
      }
#pragma unroll
      for (int v = 0; v < VEC; ++v) {
        float y = uv[v] + dv[v];
        s[v] += y; ss[v] += y * y;
      }
    }
  }
  __shared__ float reds[4][C];
  __shared__ float redss[4][C];
#pragma unroll
  for (int v = 0; v < VEC; ++v) {
    reds[wid][lane * VEC + v] = s[v];
    redss[wid][lane * VEC + v] = ss[v];
  }
  __syncthreads();
  if (tid < C) {
    float a = reds[0][tid] + reds[1][tid] + reds[2][tid] + reds[3][tid];
    float a2 = redss[0][tid] + redss[1][tid] + redss[2][tid] + redss[3][tid];
    atomicAdd(&stats[tid], a);
    atomicAdd(&stats[C + tid], a2);
  }
}

// ---------------------------------------------------------------- soft-edge apply
// Wave-per-point: lane covers CA/64 attention channels and C/64 main channels.
// Attention logits via shfl_xor wave sums (no LDS, no serial section), softmax
// redundant per lane, BN+weighted-sum with vector gathers.
template <int C, int CA>
__global__ __launch_bounds__(256) void soft_apply_kernel(const float* __restrict__ U,
                                                         const float* __restrict__ UA,
                                                         const int* __restrict__ nbr,
                                                         const float* __restrict__ stats,
                                                         const float* __restrict__ gbn,
                                                         const float* __restrict__ bbn,
                                                         const float* __restrict__ ba,
                                                         const float* __restrict__ Wb,
                                                         const float* __restrict__ bbv,
                                                         float* __restrict__ fout) {
  constexpr int VEC = C / 64;   // 4 (C=256) or 2 (C=128)
  constexpr int VA = CA / 64;   // 2 (CA=128) or 1 (CA=64)
  int tid = threadIdx.x;
  int lane = tid & 63;
  int wid = tid >> 6;
  int bn = blockIdx.x * 4 + wid;
  int b = bn >> 12;
  const int* ix = nbr + (size_t)bn * KP;
  int rows[KN];
#pragma unroll
  for (int k = 0; k < KN; ++k) rows[k] = ix[k + 1];
  // ---- attention logits
  const float* UAb = UA + ((size_t)(b << 12)) * (2 * CA);
  float da[VA], wb[VA];
  if constexpr (VA == 2) {
    float2 t = *(const float2*)(UA + (size_t)bn * (2 * CA) + CA + lane * 2);
    float2 tb = *(const float2*)(ba + lane * 2);
    float2 tw = *(const float2*)(Wb + lane * 2);
    da[0] = t.x + tb.x; da[1] = t.y + tb.y; wb[0] = tw.x; wb[1] = tw.y;
  } else {
    da[0] = UA[(size_t)bn * (2 * CA) + CA + lane] + ba[lane];
    wb[0] = Wb[lane];
  }
  float lg[KN];
#pragma unroll
  for (int k = 0; k < KN; ++k) {
    float pv = 0.f;
    if constexpr (VA == 2) {
      float2 t = *(const float2*)(UAb + (size_t)rows[k] * (2 * CA) + lane * 2);
      pv = fmaxf(t.x + da[0], 0.f) * wb[0] + fmaxf(t.y + da[1], 0.f) * wb[1];
    } else {
      float t = UAb[(size_t)rows[k] * (2 * CA) + lane];
      pv = fmaxf(t + da[0], 0.f) * wb[0];
    }
#pragma unroll
    for (int off = 32; off >= 1; off >>= 1) pv += __shfl_xor(pv, off);
    lg[k] = pv;
  }
  float bsv = bbv[0];
  float mx = -3.4e38f;
#pragma unroll
  for (int k = 0; k < KN; ++k) {
    lg[k] = (lg[k] + bsv) * (1.0f / TAU_V);
    mx = fmaxf(mx, lg[k]);
  }
  float se = 0.f;
#pragma unroll
  for (int k = 0; k < KN; ++k) { lg[k] = expf(lg[k] - mx); se += lg[k]; }
  float inv = 1.0f / se;
  // ---- BN apply + weighted sum over K
  const float* Ub = U + ((size_t)(b << 12)) * (2 * C);
  float scale[VEC], shift[VEC], dvv[VEC], acc[VEC];
#pragma unroll
  for (int v = 0; v < VEC; ++v) {
    int c = lane * VEC + v;
    float mean = stats[c] * INV_CNT;
    float var = stats[C + c] * INV_CNT - mean * mean;
    scale[v] = gbn[c] * rsqrtf(var + EPS_BN);
    shift[v] = bbn[c] - mean * scale[v];
    acc[v] = 0.f;
  }
  if constexpr (VEC == 4) {
    float4 t = *(const float4*)(U + (size_t)bn * (2 * C) + C + lane * 4);
    dvv[0] = t.x; dvv[1] = t.y; dvv[2] = t.z; dvv[3] = t.w;
  } else {
    float2 t = *(const float2*)(U + (size_t)bn * (2 * C) + C + lane * 2);
    dvv[0] = t.x; dvv[1] = t.y;
  }
#pragma unroll
  for (int k = 0; k < KN; ++k) {
    float uv[VEC];
    if constexpr (VEC == 4) {
      float4 t = *(const float4*)(Ub + (size_t)rows[k] * (2 * C) + lane * 4);
      uv[0] = t.x; uv[1] = t.y; uv[2] = t.z; uv[3] = t.w;
    } else {
      float2 t = *(const float2*)(Ub + (size_t)rows[k] * (2 * C) + lane * 2);
      uv[0] = t.x; uv[1] = t.y;
    }
#pragma unroll
    for (int v = 0; v < VEC; ++v) {
      float h = fmaxf(scale[v] * (uv[v] + dvv[v]) + shift[v], 0.f);
      acc[v] = fmaf(h, lg[k], acc[v]);
    }
  }
  if constexpr (VEC == 4) {
    float4 o = make_float4(acc[0] * inv, acc[1] * inv, acc[2] * inv, acc[3] * inv);
    *(float4*)(fout + (size_t)bn * C + lane * 4) = o;
  } else {
    float2 o = make_float2(acc[0] * inv, acc[1] * inv);
    *(float2*)(fout + (size_t)bn * C + lane * 2) = o;
  }
}

// ---------------------------------------------------------------- global attention pool
__global__ __launch_bounds__(256) void wlog_kernel(const float* __restrict__ f3,
                                                   const float* __restrict__ Wa1,
                                                   const float* __restrict__ ba1,
                                                   const float* __restrict__ Wa2,
                                                   const float* __restrict__ ba2,
                                                   float* __restrict__ wlog) {
  int tid = threadIdx.x;
  int j = tid & 63, w = tid >> 6;
  int bn = blockIdx.x * 4 + w;
  const float* f = f3 + (size_t)bn * 256;
  float acc = 0.f;
  for (int cidx = 0; cidx < 256; ++cidx) acc = fmaf(f[cidx], Wa1[cidx * 64 + j], acc);
  acc += ba1[j];
  acc = fmaxf(acc, 0.f);
  float v = acc * Wa2[j];
  for (int off = 32; off >= 1; off >>= 1) v += __shfl_down(v, off);
  if (j == 0) wlog[bn] = v + ba2[0];
}

__global__ __launch_bounds__(256) void poolstat_kernel(const float* __restrict__ wlog,
                                                       float* __restrict__ rowstat) {
  __shared__ float red[256];
  int b = blockIdx.x, tid = threadIdx.x;
  const float* wl = wlog + (size_t)b * NN;
  float mx = -3.4e38f;
  for (int n = tid; n < NN; n += 256) mx = fmaxf(mx, wl[n]);
  red[tid] = mx; __syncthreads();
  for (int s = 128; s > 0; s >>= 1) { if (tid < s) red[tid] = fmaxf(red[tid], red[tid + s]); __syncthreads(); }
  mx = red[0]; __syncthreads();
  float se = 0.f;
  for (int n = tid; n < NN; n += 256) se += expf(wl[n] - mx);
  red[tid] = se; __syncthreads();
  for (int s = 128; s > 0; s >>= 1) { if (tid < s) red[tid] += red[tid + s]; __syncthreads(); }
  if (tid == 0) { rowstat[b * 2] = mx; rowstat[b * 2 + 1] = red[0]; }
}

__global__ __launch_bounds__(256) void pooled_kernel(const float* __restrict__ f3,
                                                     const float* __restrict__ wlog,
                                                     const float* __restrict__ rowstat,
                                                     float* __restrict__ pooled) {
  int b = blockIdx.y, chunk = blockIdx.x;
  int tid = threadIdx.x;
  float mx = rowstat[b * 2], inv = 1.0f / rowstat[b * 2 + 1];
  float acc = 0.f;
  int n0 = chunk * 1024;
  for (int n = n0; n < n0 + 1024; ++n) {
    float a = expf(wlog[(size_t)b * NN + n] - mx) * inv;
    acc = fmaf(f3[((size_t)b * NN + n) * 256 + tid], a, acc);
  }
  atomicAdd(&pooled[b * 256 + tid], acc);
}

__global__ __launch_bounds__(256) void final_kernel(const float* __restrict__ pooled,
                                                    const float* __restrict__ Wfc,
                                                    const float* __restrict__ bfc,
                                                    float* __restrict__ out) {
  int b = blockIdx.x, o = threadIdx.x;
  float acc = 0.f;
  for (int c = 0; c < 256; ++c) acc = fmaf(pooled[b * 256 + c], Wfc[c * 256 + o], acc);
  acc += bfc[o];
  out[b * 256 + o] = fmaxf(acc, 0.f);
}

// ---------------------------------------------------------------- launch
static constexpr size_t align256(size_t v) { return (v + 255) & ~(size_t)255; }

extern "C" void kernel_launch(void* const* d_in, const int* in_sizes, int n_in,
                              void* d_out, int out_size, void* d_ws, size_t ws_size,
                              hipStream_t stream) {
  const float* x    = (const float*)d_in[0];
  const float* W1   = (const float*)d_in[1];
  const float* g1   = (const float*)d_in[2];
  const float* b1   = (const float*)d_in[3];
  const float* W2   = (const float*)d_in[4];
  const float* g2   = (const float*)d_in[5];
  const float* b2   = (const float*)d_in[6];
  const float* Ws2a = (const float*)d_in[7];
  const float* bs2a = (const float*)d_in[8];
  const float* Ws2b = (const float*)d_in[9];
  const float* bs2b = (const float*)d_in[10];
  const float* W3   = (const float*)d_in[11];
  const float* g3   = (const float*)d_in[12];
  const float* b3   = (const float*)d_in[13];
  const float* Ws3a = (const float*)d_in[14];
  const float* bs3a = (const float*)d_in[15];
  const float* Ws3b = (const float*)d_in[16];
  const float* bs3b = (const float*)d_in[17];
  const float* Wa1  = (const float*)d_in[18];
  const float* ba1  = (const float*)d_in[19];
  const float* Wa2  = (const float*)d_in[20];
  const float* ba2  = (const float*)d_in[21];
  const float* Wfc  = (const float*)d_in[22];
  const float* bfc  = (const float*)d_in[23];
  float* out = (float*)d_out;

  char* ws = (char*)d_ws;
  size_t off = 0;
  auto take = [&](size_t bytes) { size_t o = off; off = align256(off + bytes); return o; };
  size_t o_nbr  = take((size_t)BB * NN * KP * 4);
  size_t o_p4   = take((size_t)BB * NN * 16);
  size_t o_f1   = take((size_t)BB * NN * 64 * 4);
  size_t o_f2   = take((size_t)BB * NN * 128 * 4);
  size_t o_f3   = take((size_t)BB * NN * 256 * 4);
  size_t o_U2   = take((size_t)BB * NN * 256 * 4);
  size_t o_UA2  = take((size_t)BB * NN * 128 * 4);
  size_t o_U3   = take((size_t)BB * NN * 512 * 4);
  size_t o_UA3  = take((size_t)BB * NN * 256 * 4);
  size_t o_P2m  = take(64 * 256 * 4);
  size_t o_P2a  = take(64 * 128 * 4);
  size_t o_P3m  = take(128 * 512 * 4);
  size_t o_P3a  = take(128 * 256 * 4);
  size_t o_st   = take(896 * 4);       // stats1(128) stats2(256) stats3(512)
  size_t o_wlog = take((size_t)BB * NN * 4);
  size_t o_rs   = take(16 * 4);
  size_t o_pool = take(BB * 256 * 4);

  int*    nbr   = (int*)(ws + o_nbr);
  float4* pts4  = (float4*)(ws + o_p4);
  float*  f1    = (float*)(ws + o_f1);
  float*  f2    = (float*)(ws + o_f2);
  float*  f3    = (float*)(ws + o_f3);
  float*  U2    = (float*)(ws + o_U2);
  float*  UA2   = (float*)(ws + o_UA2);
  float*  U3    = (float*)(ws + o_U3);
  float*  UA3   = (float*)(ws + o_UA3);
  float*  P2m   = (float*)(ws + o_P2m);
  float*  P2a   = (float*)(ws + o_P2a);
  float*  P3m   = (float*)(ws + o_P3m);
  float*  P3a   = (float*)(ws + o_P3a);
  float*  stats1 = (float*)(ws + o_st);
  float*  stats2 = stats1 + 128;
  float*  stats3 = stats2 + 256;
  float*  wlog  = (float*)(ws + o_wlog);
  float*  rowst = (float*)(ws + o_rs);
  float*  pooled = (float*)(ws + o_pool);

  hipMemsetAsync(ws + o_st, 0, 896 * 4, stream);
  hipMemsetAsync(ws + o_pool, 0, BB * 256 * 4, stream);

  pack_pts_kernel<<<(BB * NN + 255) / 256, 256, 0, stream>>>(x, pts4);
  knn_kernel<<<(BB * NN) / 4, 256, 0, stream>>>(pts4, nbr);
  stats1_kernel<<<dim3(NN / 32, BB), 256, 0, stream>>>(x, nbr, W1, stats1);
  apply1_kernel<<<dim3(NN / 16, BB), 256, 0, stream>>>(x, nbr, W1, g1, b1, stats1, f1);

  pack_kernel<<<(64 * 256 + 255) / 256, 256, 0, stream>>>(W2, P2m, 64, 128);
  pack_kernel<<<(64 * 128 + 255) / 256, 256, 0, stream>>>(Ws2a, P2a, 64, 64);
  pack_kernel<<<(128 * 512 + 255) / 256, 256, 0, stream>>>(W3, P3m, 128, 256);
  pack_kernel<<<(128 * 256 + 255) / 256, 256, 0, stream>>>(Ws3a, P3a, 128, 128);

  gemm128_kernel<64><<<dim3(256 / 128, (BB * NN) / 128), 256, 0, stream>>>(f1, P2m, U2, 256);
  gemm128_kernel<64><<<dim3(128 / 128, (BB * NN) / 128), 256, 0, stream>>>(f1, P2a, UA2, 128);
  soft_stats_kernel<128><<<512, 256, 0, stream>>>(U2, nbr, stats2);
  soft_apply_kernel<128, 64><<<(BB * NN) / 4, 256, 0, stream>>>(U2, UA2, nbr, stats2, g2, b2,
                                                                bs2a, Ws2b, bs2b, f2);

  gemm128_kernel<128><<<dim3(512 / 128, (BB * NN) / 128), 256, 0, stream>>>(f2, P3m, U3, 512);
  gemm128_kernel<128><<<dim3(256 / 128, (BB * NN) / 128), 256, 0, stream>>>(f2, P3a, UA3, 256);
  soft_stats_kernel<256><<<512, 256, 0, stream>>>(U3, nbr, stats3);
  soft_apply_kernel<256, 128><<<(BB * NN) / 4, 256, 0, stream>>>(U3, UA3, nbr, stats3, g3, b3,
                                                                 bs3a, Ws3b, bs3b, f3);

  wlog_kernel<<<(BB * NN) / 4, 256, 0, stream>>>(f3, Wa1, ba1, Wa2, ba2, wlog);
  poolstat_kernel<<<BB, 256, 0, stream>>>(wlog, rowst);
  pooled_kernel<<<dim3(4, BB), 256, 0, stream>>>(f3, wlog, rowst, pooled);
  final_kernel<<<BB, 256, 0, stream>>>(pooled, Wfc, bfc, out);
}